// Round 1
// baseline (6747.590 us; speedup 1.0000x reference)
//
#include <hip/hip_runtime.h>
#include <hip/hip_bf16.h>
#include <math.h>

// Problem constants
#define N_   8
#define CIN_ 64
#define DIMS_ 64
#define NW_  8
#define T_   16
#define H_   64
#define W_   64
#define HW_  (H_ * W_)          // 4096
#define THW_ (T_ * HW_)         // 65536

// ---------------------------------------------------------------------------
// 1) std over temporal axis (ddof=1): x[8][64][16][64][64] -> std_x[8][64][64][64]
__global__ void std_kernel(const float* __restrict__ x, float* __restrict__ std_x) {
    int idx = blockIdx.x * blockDim.x + threadIdx.x;   // over 8*64*4096
    if (idx >= N_ * CIN_ * HW_) return;
    int hw = idx & (HW_ - 1);
    int nc = idx >> 12;
    const float* p = x + (size_t)nc * THW_ + hw;
    float s = 0.f, s2 = 0.f;
#pragma unroll
    for (int t = 0; t < T_; ++t) {
        float v = p[t * HW_];
        s += v;
        s2 += v * v;
    }
    float var = (s2 - s * s * (1.0f / 16.0f)) * (1.0f / 15.0f);
    std_x[idx] = sqrtf(fmaxf(var, 0.f));
}

// ---------------------------------------------------------------------------
// 2) SE conv1: std_x[8][64][64][64] * w1[16][64][5][5] VALID -> h1[8][16][60][60], relu(+b1)
__global__ void se_conv1(const float* __restrict__ std_x, const float* __restrict__ w1,
                         const float* __restrict__ b1, float* __restrict__ h1) {
    int k = blockIdx.y;   // 16
    int n = blockIdx.z;   // 8
    int ij = blockIdx.x * blockDim.x + threadIdx.x;   // 3600
    if (ij >= 60 * 60) return;
    int i = ij / 60, j = ij - i * 60;
    const float* xn = std_x + (size_t)n * CIN_ * HW_;
    const float* wk = w1 + (size_t)k * CIN_ * 25;
    float acc = b1[k];
    for (int c = 0; c < CIN_; ++c) {
        const float* xc = xn + c * HW_ + i * W_ + j;
        const float* wc = wk + c * 25;
#pragma unroll
        for (int u = 0; u < 5; ++u)
#pragma unroll
            for (int v = 0; v < 5; ++v)
                acc = fmaf(xc[u * W_ + v], wc[u * 5 + v], acc);
    }
    h1[(size_t)(n * 16 + k) * 3600 + ij] = fmaxf(acc, 0.f);
}

// ---------------------------------------------------------------------------
// 3) SE conv2: h1[8][16][60][60] * w2[32][16][5][5] VALID -> h2[8][32][56][56], relu(+b2)
__global__ void se_conv2(const float* __restrict__ h1, const float* __restrict__ w2,
                         const float* __restrict__ b2, float* __restrict__ h2) {
    int o = blockIdx.y;   // 32
    int n = blockIdx.z;   // 8
    int ij = blockIdx.x * blockDim.x + threadIdx.x;   // 3136
    if (ij >= 56 * 56) return;
    int i = ij / 56, j = ij - i * 56;
    const float* xn = h1 + (size_t)n * 16 * 3600;
    const float* wo = w2 + (size_t)o * 16 * 25;
    float acc = b2[o];
    for (int c = 0; c < 16; ++c) {
        const float* xc = xn + c * 3600 + i * 60 + j;
        const float* wc = wo + c * 25;
#pragma unroll
        for (int u = 0; u < 5; ++u)
#pragma unroll
            for (int v = 0; v < 5; ++v)
                acc = fmaf(xc[u * 60 + v], wc[u * 5 + v], acc);
    }
    h2[(size_t)(n * 32 + o) * 3136 + ij] = fmaxf(acc, 0.f);
}

// ---------------------------------------------------------------------------
// 4) max pool over spatial: h2[8][32][56][56] -> pooled[8][32]
__global__ void se_pool(const float* __restrict__ h2, float* __restrict__ pooled) {
    int no = blockIdx.x;   // 8*32
    const float* p = h2 + (size_t)no * 3136;
    float m = -1e30f;
    for (int i = threadIdx.x; i < 3136; i += 256) m = fmaxf(m, p[i]);
#pragma unroll
    for (int off = 32; off; off >>= 1) m = fmaxf(m, __shfl_down(m, off, 64));
    __shared__ float sm[4];
    if ((threadIdx.x & 63) == 0) sm[threadIdx.x >> 6] = m;
    __syncthreads();
    if (threadIdx.x == 0) {
        m = fmaxf(fmaxf(sm[0], sm[1]), fmaxf(sm[2], sm[3]));
        pooled[no] = m;
    }
}

// ---------------------------------------------------------------------------
// 5) head: logits -> softmax(phi) -> dyn_b.  Single block of 64 threads.
__global__ void se_head(const float* __restrict__ pooled, const float* __restrict__ lin_w,
                        const float* __restrict__ lin_b, const float* __restrict__ biases,
                        const int* __restrict__ epochs, float* __restrict__ phi,
                        float* __restrict__ dyn_b) {
    __shared__ float sphi[NW_][NW_];
    int tid = threadIdx.x;
    int e = epochs[0];
    float tau = (e < 10) ? (30.0f - 2.9f * (float)e) : 1.0f;
    if (tid < 64) {
        int b = tid >> 3, m = tid & 7;
        float acc = lin_b[m];
        for (int k = 0; k < 32; ++k) acc += pooled[b * 32 + k] * lin_w[m * 32 + k];
        sphi[b][m] = acc / tau;
    }
    __syncthreads();
    if (tid < 8) {
        int b = tid;
        float mx = sphi[b][0];
#pragma unroll
        for (int m = 1; m < 8; ++m) mx = fmaxf(mx, sphi[b][m]);
        float ex[8], s = 0.f;
#pragma unroll
        for (int m = 0; m < 8; ++m) { ex[m] = expf(sphi[b][m] - mx); s += ex[m]; }
        float inv = 1.0f / s;
#pragma unroll
        for (int m = 0; m < 8; ++m) { sphi[b][m] = ex[m] * inv; phi[b * 8 + m] = ex[m] * inv; }
    }
    __syncthreads();
    for (int idx = tid; idx < NW_ * DIMS_; idx += blockDim.x) {
        int b = idx >> 6, d = idx & 63;
        float acc = 0.f;
#pragma unroll
        for (int m = 0; m < 8; ++m) acc += sphi[b][m] * biases[m * DIMS_ + d];
        dyn_b[idx] = acc;
    }
}

// ---------------------------------------------------------------------------
// 6) dynamic weights, transposed for scalar loads:
//    wt[b][cin][tap][co] = sum_m phi[b][m] * weights[m][co][cin][tap]
__global__ void dyn_w_kernel(const float* __restrict__ weights, const float* __restrict__ phi,
                             float* __restrict__ wt) {
    int idx = blockIdx.x * blockDim.x + threadIdx.x;   // 64*27*64 = 110592
    int b = blockIdx.y;
    if (idx >= DIMS_ * 27 * CIN_) return;
    int co = idx & 63;
    int tap = (idx >> 6) % 27;
    int cin = idx / (64 * 27);
    size_t src = ((size_t)co * CIN_ + cin) * 27 + tap;
    float acc = 0.f;
#pragma unroll
    for (int m = 0; m < 8; ++m) acc += phi[b * 8 + m] * weights[(size_t)m * 110592 + src];
    wt[(size_t)b * 110592 + idx] = acc;
}

// ---------------------------------------------------------------------------
// 7) the main event: per-sample conv3d SAME 3x3x3 + dyn bias -> y (written to d_out)
//    One thread = one (t,h,w); all 64 output channels accumulated in VGPRs.
//    Weights are block-uniform -> scalar loads (contiguous 64 co per tap).
__global__ __launch_bounds__(256) void conv3d_kernel(
    const float* __restrict__ x,      // [8][64][16][64][64]
    const float* __restrict__ wt,     // [8][64][27][64]  (b, cin, tap, co)
    const float* __restrict__ dynb,   // [8][64]
    float* __restrict__ y)            // [8][64][16][64][64]
{
    int n = blockIdx.y;
    int s = blockIdx.x * 256 + threadIdx.x;   // 0..65535
    int t = s >> 12;
    int h = (s >> 6) & 63;
    int w = s & 63;

    float acc[DIMS_];
#pragma unroll
    for (int i = 0; i < DIMS_; ++i) acc[i] = 0.f;

    const float* xn = x + (size_t)n * CIN_ * THW_;
    const float* wn = wt + (size_t)n * CIN_ * 27 * DIMS_;

    for (int cin = 0; cin < CIN_; ++cin) {
        const float* xc = xn + cin * THW_;
        const float* wc = wn + cin * (27 * DIMS_);
#pragma unroll
        for (int dt = 0; dt < 3; ++dt) {
            int tt = t + dt - 1;
            bool tok = (unsigned)tt < (unsigned)T_;
#pragma unroll
            for (int dh = 0; dh < 3; ++dh) {
                int hh = h + dh - 1;
                bool rok = tok && ((unsigned)hh < (unsigned)H_);
                const float* xrow = xc + tt * HW_ + hh * W_ + w;
                float x0 = (rok && w >= 1)  ? xrow[-1] : 0.f;
                float x1 = rok              ? xrow[0]  : 0.f;
                float x2 = (rok && w <= 62) ? xrow[1]  : 0.f;
                const float* wrow = wc + (dt * 9 + dh * 3) * DIMS_;
#pragma unroll
                for (int co = 0; co < DIMS_; ++co) {
                    acc[co] = fmaf(x0, wrow[co], acc[co]);
                    acc[co] = fmaf(x1, wrow[DIMS_ + co], acc[co]);
                    acc[co] = fmaf(x2, wrow[2 * DIMS_ + co], acc[co]);
                }
            }
        }
    }

    const float* bb = dynb + n * DIMS_;
    size_t base = (size_t)n * DIMS_ * THW_ + s;
#pragma unroll
    for (int co = 0; co < DIMS_; ++co)
        y[base + (size_t)co * THW_] = acc[co] + bb[co];
}

// ---------------------------------------------------------------------------
// 8) BN stats: per channel c, sum and sumsq over (n, t, h, w). One block per (n,c).
__global__ void bn_stats(const float* __restrict__ y, float* __restrict__ sums) {
    int nc = blockIdx.x;          // 8*64
    int c = nc & 63;
    const float* p = y + (size_t)nc * THW_;
    float s = 0.f, s2 = 0.f;
    for (int i = threadIdx.x; i < THW_; i += 256) {
        float v = p[i];
        s += v;
        s2 += v * v;
    }
#pragma unroll
    for (int off = 32; off; off >>= 1) {
        s += __shfl_down(s, off, 64);
        s2 += __shfl_down(s2, off, 64);
    }
    __shared__ float sm[8];
    int wid = threadIdx.x >> 6;
    if ((threadIdx.x & 63) == 0) { sm[wid] = s; sm[4 + wid] = s2; }
    __syncthreads();
    if (threadIdx.x == 0) {
        s = sm[0] + sm[1] + sm[2] + sm[3];
        s2 = sm[4] + sm[5] + sm[6] + sm[7];
        atomicAdd(&sums[c], s);
        atomicAdd(&sums[64 + c], s2);
    }
}

// ---------------------------------------------------------------------------
// 9) BN normalize + relu, in place on d_out.
__global__ void bn_norm(const float* __restrict__ sums, const float* __restrict__ gamma,
                        const float* __restrict__ beta, float* __restrict__ y) {
    size_t idx = (size_t)blockIdx.x * 256 + threadIdx.x;   // 33,554,432
    int c = (int)((idx >> 16) & 63);                       // block-uniform
    const float cnt = (float)(N_ * THW_);
    float mean = sums[c] / cnt;
    float var = sums[64 + c] / cnt - mean * mean;
    float inv = rsqrtf(var + 1e-5f);
    float v = y[idx];
    v = (v - mean) * (gamma[c] * inv) + (beta[c] - mean * 0.f);
    y[idx] = fmaxf(v, 0.f);
}

// ---------------------------------------------------------------------------
extern "C" void kernel_launch(void* const* d_in, const int* in_sizes, int n_in,
                              void* d_out, int out_size, void* d_ws, size_t ws_size,
                              hipStream_t stream) {
    const float* x       = (const float*)d_in[0];
    const float* weights = (const float*)d_in[1];
    const float* biases  = (const float*)d_in[2];
    const float* se_w1   = (const float*)d_in[3];
    const float* se_b1   = (const float*)d_in[4];
    const float* se_w2   = (const float*)d_in[5];
    const float* se_b2   = (const float*)d_in[6];
    const float* lin_w   = (const float*)d_in[7];
    const float* lin_b   = (const float*)d_in[8];
    const float* gamma   = (const float*)d_in[9];
    const float* beta    = (const float*)d_in[10];
    const int*   epochs  = (const int*)d_in[11];

    float* out = (float*)d_out;
    float* ws = (float*)d_ws;

    // workspace layout (floats)
    const size_t STD_OFF   = 0;                       // 2,097,152
    const size_t H1_OFF    = STD_OFF + 2097152;       // 460,800
    const size_t H2_OFF    = H1_OFF + 460800;         // 802,816
    const size_t POOL_OFF  = H2_OFF + 802816;         // 256
    const size_t PHI_OFF   = POOL_OFF + 256;          // 64
    const size_t DYNB_OFF  = PHI_OFF + 64;            // 512
    const size_t WT_OFF    = DYNB_OFF + 512;          // 884,736
    const size_t SUMS_OFF  = WT_OFF + 884736;         // 128

    float* std_x  = ws + STD_OFF;
    float* h1     = ws + H1_OFF;
    float* h2     = ws + H2_OFF;
    float* pooled = ws + POOL_OFF;
    float* phi    = ws + PHI_OFF;
    float* dynb   = ws + DYNB_OFF;
    float* wt     = ws + WT_OFF;
    float* sums   = ws + SUMS_OFF;

    hipMemsetAsync(sums, 0, 128 * sizeof(float), stream);

    // 1) temporal std
    std_kernel<<<(N_ * CIN_ * HW_) / 256, 256, 0, stream>>>(x, std_x);

    // 2,3) SE convs
    se_conv1<<<dim3((3600 + 255) / 256, 16, 8), 256, 0, stream>>>(std_x, se_w1, se_b1, h1);
    se_conv2<<<dim3((3136 + 255) / 256, 32, 8), 256, 0, stream>>>(h1, se_w2, se_b2, h2);

    // 4) max pool
    se_pool<<<N_ * 32, 256, 0, stream>>>(h2, pooled);

    // 5) head: phi + dyn_b
    se_head<<<1, 64, 0, stream>>>(pooled, lin_w, lin_b, biases, epochs, phi, dynb);

    // 6) dynamic weights (transposed)
    dyn_w_kernel<<<dim3((110592 + 255) / 256, 8), 256, 0, stream>>>(weights, phi, wt);

    // 7) conv3d + bias -> d_out (as y scratch)
    conv3d_kernel<<<dim3(THW_ / 256, N_), 256, 0, stream>>>(x, wt, dynb, out);

    // 8) BN stats
    bn_stats<<<N_ * DIMS_, 256, 0, stream>>>(out, sums);

    // 9) BN normalize + relu in place
    bn_norm<<<(size_t)N_ * DIMS_ * THW_ / 256, 256, 0, stream>>>(sums, gamma, beta, out);
}

// Round 2
// 996.770 us; speedup vs baseline: 6.7695x; 6.7695x over previous
//
#include <hip/hip_runtime.h>
#include <hip/hip_bf16.h>
#include <math.h>

// Problem constants
#define N_   8
#define CIN_ 64
#define DIMS_ 64
#define NW_  8
#define T_   16
#define H_   64
#define W_   64
#define HW_  (H_ * W_)          // 4096
#define THW_ (T_ * HW_)         // 65536

typedef short bf16x8 __attribute__((ext_vector_type(8)));
typedef float f32x4 __attribute__((ext_vector_type(4)));

__device__ __forceinline__ unsigned short f2bf(float f) {
    union { float f; unsigned u; } a; a.f = f;
    unsigned r = a.u + 0x7fffu + ((a.u >> 16) & 1u);   // RNE
    return (unsigned short)(r >> 16);
}

// LDS geometry for conv3d staging: [3 t][10 h][66 w][12 cin-halfwords (8 used)]
#define CS_   12
#define HSTR_ (66 * CS_)        // 792
#define TSTR_ (10 * HSTR_)      // 7920
#define LDSH_ (3 * TSTR_)       // 23760 halfwords = 47520 B

__device__ __forceinline__ constexpr int offx(int tap) {
    return (tap / 9) * TSTR_ + ((tap % 9) / 3) * HSTR_ + ((tap % 3) - 1) * CS_;
}

// ---------------------------------------------------------------------------
// 1) std over temporal axis (ddof=1)
__global__ void std_kernel(const float* __restrict__ x, float* __restrict__ std_x) {
    int idx = blockIdx.x * blockDim.x + threadIdx.x;
    if (idx >= N_ * CIN_ * HW_) return;
    int hw = idx & (HW_ - 1);
    int nc = idx >> 12;
    const float* p = x + (size_t)nc * THW_ + hw;
    float s = 0.f, s2 = 0.f;
#pragma unroll
    for (int t = 0; t < T_; ++t) {
        float v = p[t * HW_];
        s += v;
        s2 += v * v;
    }
    float var = (s2 - s * s * (1.0f / 16.0f)) * (1.0f / 15.0f);
    std_x[idx] = sqrtf(fmaxf(var, 0.f));
}

// ---------------------------------------------------------------------------
// 2) SE conv1
__global__ void se_conv1(const float* __restrict__ std_x, const float* __restrict__ w1,
                         const float* __restrict__ b1, float* __restrict__ h1) {
    int k = blockIdx.y;
    int n = blockIdx.z;
    int ij = blockIdx.x * blockDim.x + threadIdx.x;
    if (ij >= 60 * 60) return;
    int i = ij / 60, j = ij - i * 60;
    const float* xn = std_x + (size_t)n * CIN_ * HW_;
    const float* wk = w1 + (size_t)k * CIN_ * 25;
    float acc = b1[k];
    for (int c = 0; c < CIN_; ++c) {
        const float* xc = xn + c * HW_ + i * W_ + j;
        const float* wc = wk + c * 25;
#pragma unroll
        for (int u = 0; u < 5; ++u)
#pragma unroll
            for (int v = 0; v < 5; ++v)
                acc = fmaf(xc[u * W_ + v], wc[u * 5 + v], acc);
    }
    h1[(size_t)(n * 16 + k) * 3600 + ij] = fmaxf(acc, 0.f);
}

// ---------------------------------------------------------------------------
// 3) SE conv2
__global__ void se_conv2(const float* __restrict__ h1, const float* __restrict__ w2,
                         const float* __restrict__ b2, float* __restrict__ h2) {
    int o = blockIdx.y;
    int n = blockIdx.z;
    int ij = blockIdx.x * blockDim.x + threadIdx.x;
    if (ij >= 56 * 56) return;
    int i = ij / 56, j = ij - i * 56;
    const float* xn = h1 + (size_t)n * 16 * 3600;
    const float* wo = w2 + (size_t)o * 16 * 25;
    float acc = b2[o];
    for (int c = 0; c < 16; ++c) {
        const float* xc = xn + c * 3600 + i * 60 + j;
        const float* wc = wo + c * 25;
#pragma unroll
        for (int u = 0; u < 5; ++u)
#pragma unroll
            for (int v = 0; v < 5; ++v)
                acc = fmaf(xc[u * 60 + v], wc[u * 5 + v], acc);
    }
    h2[(size_t)(n * 32 + o) * 3136 + ij] = fmaxf(acc, 0.f);
}

// ---------------------------------------------------------------------------
// 4) max pool
__global__ void se_pool(const float* __restrict__ h2, float* __restrict__ pooled) {
    int no = blockIdx.x;
    const float* p = h2 + (size_t)no * 3136;
    float m = -1e30f;
    for (int i = threadIdx.x; i < 3136; i += 256) m = fmaxf(m, p[i]);
#pragma unroll
    for (int off = 32; off; off >>= 1) m = fmaxf(m, __shfl_down(m, off, 64));
    __shared__ float sm[4];
    if ((threadIdx.x & 63) == 0) sm[threadIdx.x >> 6] = m;
    __syncthreads();
    if (threadIdx.x == 0) {
        m = fmaxf(fmaxf(sm[0], sm[1]), fmaxf(sm[2], sm[3]));
        pooled[no] = m;
    }
}

// ---------------------------------------------------------------------------
// 5) head: logits -> softmax(phi) -> dyn_b
__global__ void se_head(const float* __restrict__ pooled, const float* __restrict__ lin_w,
                        const float* __restrict__ lin_b, const float* __restrict__ biases,
                        const int* __restrict__ epochs, float* __restrict__ phi,
                        float* __restrict__ dyn_b) {
    __shared__ float sphi[NW_][NW_];
    int tid = threadIdx.x;
    int e = epochs[0];
    float tau = (e < 10) ? (30.0f - 2.9f * (float)e) : 1.0f;
    if (tid < 64) {
        int b = tid >> 3, m = tid & 7;
        float acc = lin_b[m];
        for (int k = 0; k < 32; ++k) acc += pooled[b * 32 + k] * lin_w[m * 32 + k];
        sphi[b][m] = acc / tau;
    }
    __syncthreads();
    if (tid < 8) {
        int b = tid;
        float mx = sphi[b][0];
#pragma unroll
        for (int m = 1; m < 8; ++m) mx = fmaxf(mx, sphi[b][m]);
        float ex[8], s = 0.f;
#pragma unroll
        for (int m = 0; m < 8; ++m) { ex[m] = expf(sphi[b][m] - mx); s += ex[m]; }
        float inv = 1.0f / s;
#pragma unroll
        for (int m = 0; m < 8; ++m) { sphi[b][m] = ex[m] * inv; phi[b * 8 + m] = ex[m] * inv; }
    }
    __syncthreads();
    for (int idx = tid; idx < NW_ * DIMS_; idx += blockDim.x) {
        int b = idx >> 6, d = idx & 63;
        float acc = 0.f;
#pragma unroll
        for (int m = 0; m < 8; ++m) acc += sphi[b][m] * biases[m * DIMS_ + d];
        dyn_b[idx] = acc;
    }
}

// ---------------------------------------------------------------------------
// 6) dynamic weights in bf16, layout wtb[b][28 taps][co][cin], tap 27 zeroed.
__global__ void dyn_w_bf16(const float* __restrict__ weights, const float* __restrict__ phi,
                           unsigned short* __restrict__ wtb) {
    int flat = blockIdx.x * blockDim.x + threadIdx.x;   // 28*4096 = 114688
    int b = blockIdx.y;
    if (flat >= 28 * 4096) return;
    int tap = flat >> 12;
    int cc = flat & 4095;            // co*64 + cin
    unsigned short v = 0;
    if (tap < 27) {
        int co = cc >> 6, cin = cc & 63;
        size_t src = ((size_t)(co * 64) + cin) * 27 + tap;   // within one m: [co][cin][tap]
        float acc = 0.f;
#pragma unroll
        for (int m = 0; m < 8; ++m)
            acc += phi[b * 8 + m] * weights[(size_t)m * (64 * 64 * 27) + src];
        v = f2bf(acc);
    }
    wtb[(size_t)b * (28 * 4096) + flat] = v;
}

// ---------------------------------------------------------------------------
// 7) conv3d via MFMA implicit GEMM.
//    Block: (hb, t, n); 512 threads = 8 waves; each wave one output h-row (64 w) x 64 co.
//    K = 8 cin-chunks x 7 K-steps (4 taps x 8 cin each).
__global__ __launch_bounds__(512, 4) void conv3d_mfma(
    const float* __restrict__ x,              // [8][64][16][64][64] fp32
    const unsigned short* __restrict__ wtb,   // [8][28][64][64] bf16
    const float* __restrict__ dynb,           // [8][64]
    float* __restrict__ y)                    // [8][64][16][64][64] fp32
{
    __shared__ unsigned short xs[LDSH_];

    const int hb = blockIdx.x, t = blockIdx.y, n = blockIdx.z;
    const int tid = threadIdx.x;
    const int lane = tid & 63, wid = tid >> 6;   // wid 0..7
    const int lw = lane & 15;                    // A: co-within-tile; B: sp col
    const int g = lane >> 4;                     // tap-within-quad select
    const int hbase = hb * 8;

    // zero the w-pad columns (w'=0 and w'=65), all 12 halfwords per row
    for (int i = tid; i < 360; i += 512) {       // 360 u32 = 720 halfwords
        int c6 = i % 6;                          // u32 within row (12 halfwords)
        int u = i / 6;                           // 0..59
        int side = u & 1;
        int th = u >> 1;                         // 0..29
        int tp = th / 10, hp = th % 10;
        int addr = tp * TSTR_ + hp * HSTR_ + (side ? 65 * CS_ : 0) + c6 * 2;
        *(unsigned*)&xs[addr] = 0u;
    }

    f32x4 acc[4][4];
#pragma unroll
    for (int ct = 0; ct < 4; ++ct)
#pragma unroll
        for (int s = 0; s < 4; ++s)
            acc[ct][s] = (f32x4){0.f, 0.f, 0.f, 0.f};

    int bsp[4];
#pragma unroll
    for (int s = 0; s < 4; ++s)
        bsp[s] = wid * HSTR_ + ((s << 4) + lw + 1) * CS_;

    const unsigned short* wn = wtb + (size_t)n * (28 * 4096);
    const float* xn = x + (size_t)n * (CIN_ * THW_);
    const int wst = tid & 63, slot = tid >> 6;

    for (int c8 = 0; c8 < 8; ++c8) {             // cin chunk of 8
        __syncthreads();
        // ---- stage chunk: 120 units (3t x 10h x 4 cin-pairs), 8 slots -> 15 iters
        for (int it = 0; it < 15; ++it) {
            int u = (it << 3) + slot;            // 0..119
            int tp = u / 40;
            int rem = u - tp * 40;
            int hp = rem >> 2, pc = rem & 3;
            int cin = (c8 << 3) + (pc << 1);
            int gt = t + tp - 1, gh = hbase + hp - 1;
            float v0 = 0.f, v1 = 0.f;
            if (((unsigned)gt < 16u) & ((unsigned)gh < 64u)) {
                const float* px = xn + (((size_t)cin << 4) + gt) * HW_ + (gh << 6) + wst;
                v0 = px[0];
                v1 = px[THW_];
            }
            unsigned pr = (unsigned)f2bf(v0) | ((unsigned)f2bf(v1) << 16);
            *(unsigned*)&xs[tp * TSTR_ + hp * HSTR_ + (wst + 1) * CS_ + (pc << 1)] = pr;
        }
        __syncthreads();

        // ---- compute: 7 K-steps of (4 taps x 8 cin)
        const int wq = (lw << 6) + (c8 << 3);    // co-row base + cin offset (halfwords)
#pragma unroll
        for (int p = 0; p < 7; ++p) {
            const int tap = 4 * p + g;           // 0..27 (27 = zero-weight pad tap)
            const int xo = (g == 0) ? offx(4 * p)
                         : (g == 1) ? offx(4 * p + 1)
                         : (g == 2) ? offx(4 * p + 2)
                                    : offx(4 * p + 3 > 26 ? 26 : 4 * p + 3);
            bf16x8 af[4];
#pragma unroll
            for (int ct = 0; ct < 4; ++ct)
                af[ct] = *(const bf16x8*)(wn + tap * 4096 + (ct << 10) + wq);
#pragma unroll
            for (int s = 0; s < 4; ++s) {
                union { bf16x8 v; unsigned long long q2[2]; } bx;
                int a0 = bsp[s] + xo;
                bx.q2[0] = *(const unsigned long long*)&xs[a0];
                bx.q2[1] = *(const unsigned long long*)&xs[a0 + 4];
#pragma unroll
                for (int ct = 0; ct < 4; ++ct)
                    acc[ct][s] = __builtin_amdgcn_mfma_f32_16x16x32_bf16(af[ct], bx.v, acc[ct][s], 0, 0, 0);
            }
        }
    }

    // ---- epilogue: C/D layout col(sp)=lane&15, row(co)=(lane>>4)*4+r
    const int row4 = (lane >> 4) << 2;
    const float* db = dynb + n * DIMS_;
#pragma unroll
    for (int ct = 0; ct < 4; ++ct) {
        const int co = ct * 16 + row4;
#pragma unroll
        for (int s = 0; s < 4; ++s) {
            const int ww = (s << 4) + lw;
            size_t base = ((((size_t)n * DIMS_ + co) * T_ + t) << 12) + ((hbase + wid) << 6) + ww;
#pragma unroll
            for (int r = 0; r < 4; ++r)
                y[base + ((size_t)r << 16)] = acc[ct][s][r] + db[co + r];
        }
    }
}

// ---------------------------------------------------------------------------
// 8) BN stats
__global__ void bn_stats(const float* __restrict__ y, float* __restrict__ sums) {
    int nc = blockIdx.x;
    int c = nc & 63;
    const float* p = y + (size_t)nc * THW_;
    float s = 0.f, s2 = 0.f;
    for (int i = threadIdx.x; i < THW_; i += 256) {
        float v = p[i];
        s += v;
        s2 += v * v;
    }
#pragma unroll
    for (int off = 32; off; off >>= 1) {
        s += __shfl_down(s, off, 64);
        s2 += __shfl_down(s2, off, 64);
    }
    __shared__ float sm[8];
    int wid = threadIdx.x >> 6;
    if ((threadIdx.x & 63) == 0) { sm[wid] = s; sm[4 + wid] = s2; }
    __syncthreads();
    if (threadIdx.x == 0) {
        s = sm[0] + sm[1] + sm[2] + sm[3];
        s2 = sm[4] + sm[5] + sm[6] + sm[7];
        atomicAdd(&sums[c], s);
        atomicAdd(&sums[64 + c], s2);
    }
}

// ---------------------------------------------------------------------------
// 9) BN normalize + relu in place
__global__ void bn_norm(const float* __restrict__ sums, const float* __restrict__ gamma,
                        const float* __restrict__ beta, float* __restrict__ y) {
    size_t idx = (size_t)blockIdx.x * 256 + threadIdx.x;
    int c = (int)((idx >> 16) & 63);
    const float cnt = (float)(N_ * THW_);
    float mean = sums[c] / cnt;
    float var = sums[64 + c] / cnt - mean * mean;
    float inv = rsqrtf(var + 1e-5f);
    float v = y[idx];
    v = (v - mean) * (gamma[c] * inv) + beta[c];
    y[idx] = fmaxf(v, 0.f);
}

// ---------------------------------------------------------------------------
extern "C" void kernel_launch(void* const* d_in, const int* in_sizes, int n_in,
                              void* d_out, int out_size, void* d_ws, size_t ws_size,
                              hipStream_t stream) {
    const float* x       = (const float*)d_in[0];
    const float* weights = (const float*)d_in[1];
    const float* biases  = (const float*)d_in[2];
    const float* se_w1   = (const float*)d_in[3];
    const float* se_b1   = (const float*)d_in[4];
    const float* se_w2   = (const float*)d_in[5];
    const float* se_b2   = (const float*)d_in[6];
    const float* lin_w   = (const float*)d_in[7];
    const float* lin_b   = (const float*)d_in[8];
    const float* gamma   = (const float*)d_in[9];
    const float* beta    = (const float*)d_in[10];
    const int*   epochs  = (const int*)d_in[11];

    float* out = (float*)d_out;
    float* ws = (float*)d_ws;

    // workspace layout (float slots)
    const size_t STD_OFF  = 0;                        // 2,097,152
    const size_t H1_OFF   = STD_OFF + 2097152;        // 460,800
    const size_t H2_OFF   = H1_OFF + 460800;          // 802,816
    const size_t POOL_OFF = H2_OFF + 802816;          // 256
    const size_t PHI_OFF  = POOL_OFF + 256;           // 64
    const size_t DYNB_OFF = PHI_OFF + 64;             // 512
    const size_t SUMS_OFF = DYNB_OFF + 512;           // 128
    const size_t WTB_OFF  = SUMS_OFF + 128;           // 458,752 float slots (bf16 x 917,504)

    float* std_x  = ws + STD_OFF;
    float* h1     = ws + H1_OFF;
    float* h2     = ws + H2_OFF;
    float* pooled = ws + POOL_OFF;
    float* phi    = ws + PHI_OFF;
    float* dynb   = ws + DYNB_OFF;
    float* sums   = ws + SUMS_OFF;
    unsigned short* wtb = (unsigned short*)(ws + WTB_OFF);

    hipMemsetAsync(sums, 0, 128 * sizeof(float), stream);

    std_kernel<<<(N_ * CIN_ * HW_) / 256, 256, 0, stream>>>(x, std_x);
    se_conv1<<<dim3((3600 + 255) / 256, 16, 8), 256, 0, stream>>>(std_x, se_w1, se_b1, h1);
    se_conv2<<<dim3((3136 + 255) / 256, 32, 8), 256, 0, stream>>>(h1, se_w2, se_b2, h2);
    se_pool<<<N_ * 32, 256, 0, stream>>>(h2, pooled);
    se_head<<<1, 64, 0, stream>>>(pooled, lin_w, lin_b, biases, epochs, phi, dynb);

    dyn_w_bf16<<<dim3(448, 8), 256, 0, stream>>>(weights, phi, wtb);

    conv3d_mfma<<<dim3(8, 16, 8), 512, 0, stream>>>(x, wtb, dynb, out);

    bn_stats<<<N_ * DIMS_, 256, 0, stream>>>(out, sums);
    bn_norm<<<(size_t)N_ * DIMS_ * THW_ / 256, 256, 0, stream>>>(sums, gamma, beta, out);
}

// Round 3
// 522.275 us; speedup vs baseline: 12.9196x; 1.9085x over previous
//
#include <hip/hip_runtime.h>
#include <hip/hip_bf16.h>
#include <math.h>

// Problem constants
#define N_   8
#define CIN_ 64
#define DIMS_ 64
#define NW_  8
#define T_   16
#define H_   64
#define W_   64
#define HW_  (H_ * W_)          // 4096
#define THW_ (T_ * HW_)         // 65536

typedef short bf16x8 __attribute__((ext_vector_type(8)));
typedef float f32x4 __attribute__((ext_vector_type(4)));

__device__ __forceinline__ unsigned short f2bf(float f) {
    union { float f; unsigned u; } a; a.f = f;
    unsigned r = a.u + 0x7fffu + ((a.u >> 16) & 1u);   // RNE
    return (unsigned short)(r >> 16);
}

// ---------------------------------------------------------------------------
// legacy LDS geometry (fallback conv): [3t][10h][66w][12 hw]
#define CS_   12
#define HSTR_ (66 * CS_)
#define TSTR_ (10 * HSTR_)
#define LDSH_ (3 * TSTR_)

__device__ __forceinline__ constexpr int offx(int tap) {
    return (tap / 9) * TSTR_ + ((tap % 9) / 3) * HSTR_ + ((tap % 3) - 1) * CS_;
}

// fast-path LDS geometry: [3t][10h][66w][8 hw], 16B per (w) slot
#define CS8_ 8
#define HS8_ (66 * CS8_)        // 528
#define TS8_ (10 * HS8_)        // 5280
#define BUF8_ (3 * TS8_)        // 15840 halfwords = 31680 B

__device__ __forceinline__ constexpr int offx8(int tap) {
    return (tap / 9) * TS8_ + ((tap % 9) / 3) * HS8_ + ((tap % 3) - 1) * CS8_;
}

// ---------------------------------------------------------------------------
// 1) std over temporal axis (ddof=1)
__global__ void std_kernel(const float* __restrict__ x, float* __restrict__ std_x) {
    int idx = blockIdx.x * blockDim.x + threadIdx.x;
    if (idx >= N_ * CIN_ * HW_) return;
    int hw = idx & (HW_ - 1);
    int nc = idx >> 12;
    const float* p = x + (size_t)nc * THW_ + hw;
    float s = 0.f, s2 = 0.f;
#pragma unroll
    for (int t = 0; t < T_; ++t) {
        float v = p[t * HW_];
        s += v;
        s2 += v * v;
    }
    float var = (s2 - s * s * (1.0f / 16.0f)) * (1.0f / 15.0f);
    std_x[idx] = sqrtf(fmaxf(var, 0.f));
}

// ---------------------------------------------------------------------------
// 1b) x -> xb bf16, layout [n][c8][t][h][w][8cin]
__global__ void xb_kernel(const float* __restrict__ x, unsigned short* __restrict__ xb) {
    int idx = blockIdx.x * 256 + threadIdx.x;      // 4,194,304
    int w = idx & 63, h = (idx >> 6) & 63, t = (idx >> 12) & 15;
    int c8 = (idx >> 16) & 7, n = idx >> 19;
    const float* px = x + ((((size_t)(n * 64 + c8 * 8)) * 16 + t) << 12) + (h << 6) + w;
    union { unsigned short u[8]; int4 v; } o;
#pragma unroll
    for (int j = 0; j < 8; ++j) o.u[j] = f2bf(px[(size_t)j * THW_]);
    *(int4*)&xb[(size_t)idx * 8] = o.v;
}

// ---------------------------------------------------------------------------
// 1c) transpose SE weights: w1[16][64][25]->w1t[64][25][16]; w2[32][16][25]->w2t[16][25][32]
__global__ void wtrans(const float* __restrict__ w1, const float* __restrict__ w2,
                       float* __restrict__ w1t, float* __restrict__ w2t) {
    int i = blockIdx.x * 256 + threadIdx.x;
    if (i < 25600) {
        int k = i / 1600, c = (i / 25) % 64, tap = i % 25;
        w1t[(c * 25 + tap) * 16 + k] = w1[i];
    } else if (i < 38400) {
        int j = i - 25600;
        int o = j / 400, c = (j / 25) % 16, tap = j % 25;
        w2t[(c * 25 + tap) * 32 + o] = w2[j];
    }
}

// ---------------------------------------------------------------------------
// 2) SE conv1: 8 k-outputs per thread, uniform (scalar) weight reads
__global__ __launch_bounds__(64) void se_conv1b(const float* __restrict__ std_x,
        const float* __restrict__ w1t, const float* __restrict__ b1, float* __restrict__ h1) {
    int n = blockIdx.y, ks = blockIdx.z * 8;
    int ij = blockIdx.x * 64 + threadIdx.x;
    if (ij >= 3600) return;
    int i = ij / 60, j = ij - i * 60;
    const float* xn = std_x + (size_t)n * CIN_ * HW_ + i * W_ + j;
    float acc[8];
#pragma unroll
    for (int q = 0; q < 8; ++q) acc[q] = b1[ks + q];
    for (int c = 0; c < CIN_; ++c) {
        const float* xc = xn + c * HW_;
        float xv[25];
#pragma unroll
        for (int u = 0; u < 5; ++u)
#pragma unroll
            for (int v = 0; v < 5; ++v) xv[u * 5 + v] = xc[u * W_ + v];
        const float* wc = w1t + c * 400 + ks;
#pragma unroll
        for (int tap = 0; tap < 25; ++tap)
#pragma unroll
            for (int q = 0; q < 8; ++q)
                acc[q] = fmaf(xv[tap], wc[tap * 16 + q], acc[q]);
    }
#pragma unroll
    for (int q = 0; q < 8; ++q)
        h1[((size_t)(n * 16 + ks + q)) * 3600 + ij] = fmaxf(acc[q], 0.f);
}

// ---------------------------------------------------------------------------
// 3) SE conv2: 8 o-outputs per thread
__global__ __launch_bounds__(64) void se_conv2b(const float* __restrict__ h1,
        const float* __restrict__ w2t, const float* __restrict__ b2, float* __restrict__ h2) {
    int n = blockIdx.y, os = blockIdx.z * 8;
    int ij = blockIdx.x * 64 + threadIdx.x;
    if (ij >= 3136) return;
    int i = ij / 56, j = ij - i * 56;
    const float* xn = h1 + (size_t)n * 16 * 3600 + i * 60 + j;
    float acc[8];
#pragma unroll
    for (int q = 0; q < 8; ++q) acc[q] = b2[os + q];
    for (int c = 0; c < 16; ++c) {
        const float* xc = xn + c * 3600;
        float xv[25];
#pragma unroll
        for (int u = 0; u < 5; ++u)
#pragma unroll
            for (int v = 0; v < 5; ++v) xv[u * 5 + v] = xc[u * 60 + v];
        const float* wc = w2t + c * 800 + os;
#pragma unroll
        for (int tap = 0; tap < 25; ++tap)
#pragma unroll
            for (int q = 0; q < 8; ++q)
                acc[q] = fmaf(xv[tap], wc[tap * 32 + q], acc[q]);
    }
#pragma unroll
    for (int q = 0; q < 8; ++q)
        h2[((size_t)(n * 32 + os + q)) * 3136 + ij] = fmaxf(acc[q], 0.f);
}

// ---------------------------------------------------------------------------
// 4) max pool
__global__ void se_pool(const float* __restrict__ h2, float* __restrict__ pooled) {
    int no = blockIdx.x;
    const float* p = h2 + (size_t)no * 3136;
    float m = -1e30f;
    for (int i = threadIdx.x; i < 3136; i += 256) m = fmaxf(m, p[i]);
#pragma unroll
    for (int off = 32; off; off >>= 1) m = fmaxf(m, __shfl_down(m, off, 64));
    __shared__ float sm[4];
    if ((threadIdx.x & 63) == 0) sm[threadIdx.x >> 6] = m;
    __syncthreads();
    if (threadIdx.x == 0) {
        m = fmaxf(fmaxf(sm[0], sm[1]), fmaxf(sm[2], sm[3]));
        pooled[no] = m;
    }
}

// ---------------------------------------------------------------------------
// 5) head: logits -> softmax(phi) -> dyn_b
__global__ void se_head(const float* __restrict__ pooled, const float* __restrict__ lin_w,
                        const float* __restrict__ lin_b, const float* __restrict__ biases,
                        const int* __restrict__ epochs, float* __restrict__ phi,
                        float* __restrict__ dyn_b) {
    __shared__ float sphi[NW_][NW_];
    int tid = threadIdx.x;
    int e = epochs[0];
    float tau = (e < 10) ? (30.0f - 2.9f * (float)e) : 1.0f;
    if (tid < 64) {
        int b = tid >> 3, m = tid & 7;
        float acc = lin_b[m];
        for (int k = 0; k < 32; ++k) acc += pooled[b * 32 + k] * lin_w[m * 32 + k];
        sphi[b][m] = acc / tau;
    }
    __syncthreads();
    if (tid < 8) {
        int b = tid;
        float mx = sphi[b][0];
#pragma unroll
        for (int m = 1; m < 8; ++m) mx = fmaxf(mx, sphi[b][m]);
        float ex[8], s = 0.f;
#pragma unroll
        for (int m = 0; m < 8; ++m) { ex[m] = expf(sphi[b][m] - mx); s += ex[m]; }
        float inv = 1.0f / s;
#pragma unroll
        for (int m = 0; m < 8; ++m) { sphi[b][m] = ex[m] * inv; phi[b * 8 + m] = ex[m] * inv; }
    }
    __syncthreads();
    for (int idx = tid; idx < NW_ * DIMS_; idx += blockDim.x) {
        int b = idx >> 6, d = idx & 63;
        float acc = 0.f;
#pragma unroll
        for (int m = 0; m < 8; ++m) acc += sphi[b][m] * biases[m * DIMS_ + d];
        dyn_b[idx] = acc;
    }
}

// ---------------------------------------------------------------------------
// 6) dynamic weights bf16, wtb[b][28][co][cin], tap 27 zero
__global__ void dyn_w_bf16(const float* __restrict__ weights, const float* __restrict__ phi,
                           unsigned short* __restrict__ wtb) {
    int flat = blockIdx.x * blockDim.x + threadIdx.x;
    int b = blockIdx.y;
    if (flat >= 28 * 4096) return;
    int tap = flat >> 12;
    int cc = flat & 4095;
    unsigned short v = 0;
    if (tap < 27) {
        int co = cc >> 6, cin = cc & 63;
        size_t src = ((size_t)(co * 64) + cin) * 27 + tap;
        float acc = 0.f;
#pragma unroll
        for (int m = 0; m < 8; ++m)
            acc += phi[b * 8 + m] * weights[(size_t)m * (64 * 64 * 27) + src];
        v = f2bf(acc);
    }
    wtb[(size_t)b * (28 * 4096) + flat] = v;
}

// ---------------------------------------------------------------------------
// 7) FAST conv3d: global_load_lds staging from xb, double-buffered, fused BN stats
__global__ __launch_bounds__(512, 4) void conv3d_mfma2(
    const unsigned short* __restrict__ xb,    // [8][8][16][64][64][8] bf16
    const unsigned short* __restrict__ wtb,   // [8][28][64][64] bf16
    const float* __restrict__ dynb,           // [8][64]
    float* __restrict__ y,                    // [8][64][16][64][64] fp32
    float* __restrict__ sums)                 // [128]
{
    __shared__ __align__(16) unsigned short xs[2 * BUF8_];
    __shared__ float bnred[128];

    const int hb = blockIdx.x, t = blockIdx.y, n = blockIdx.z;
    const int tid = threadIdx.x;
    const int lane = tid & 63, wid = tid >> 6;
    const int lw = lane & 15, g = lane >> 4;
    const int hbase = hb * 8;

    // zero both LDS buffers (covers halo rows + w-pad slots) and bnred
    for (int i = tid; i < (2 * BUF8_) / 8; i += 512)
        *(int4*)&xs[i * 8] = (int4){0, 0, 0, 0};
    if (tid < 128) bnred[tid] = 0.f;
    __syncthreads();

    auto STAGE = [&](int c8, int bufbase) {
#pragma unroll
        for (int k = 0; k < 4; ++k) {
            int r = wid + (k << 3);                    // 0..31, rows 0..29 used
            if (r < 30) {                              // wave-uniform
                int tp = (r >= 20) ? 2 : (r >= 10 ? 1 : 0);
                int hp = r - tp * 10;
                int gt = t + tp - 1, gh = hbase + hp - 1;
                if (((unsigned)gt < 16u) && ((unsigned)gh < 64u)) {
                    const unsigned short* gp =
                        xb + (size_t)((((n * 8 + c8) * 16 + gt) * 64 + gh) * 64 + lane) * 8;
                    const unsigned short* lp = &xs[bufbase + tp * TS8_ + hp * HS8_ + CS8_];
                    __builtin_amdgcn_global_load_lds(
                        (const __attribute__((address_space(1))) void*)gp,
                        (__attribute__((address_space(3))) void*)lp, 16, 0, 0);
                }
            }
        }
    };

    f32x4 acc[4][4];
#pragma unroll
    for (int ct = 0; ct < 4; ++ct)
#pragma unroll
        for (int s = 0; s < 4; ++s)
            acc[ct][s] = (f32x4){0.f, 0.f, 0.f, 0.f};

    int bsp[4];
#pragma unroll
    for (int s = 0; s < 4; ++s)
        bsp[s] = wid * HS8_ + ((s << 4) + lw + 1) * CS8_;

    const unsigned short* wn = wtb + (size_t)n * (28 * 4096);

    STAGE(0, 0);
    __syncthreads();    // drains vmcnt -> chunk 0 staged

    for (int c8 = 0; c8 < 8; ++c8) {
        const int cur = (c8 & 1) * BUF8_;
        if (c8 < 7) STAGE(c8 + 1, BUF8_ - cur);        // prefetch next chunk

        const int wq = (lw << 6) + (c8 << 3);
#pragma unroll
        for (int p = 0; p < 7; ++p) {
            const int tap = 4 * p + g;                 // 27 = zero-weight pad
            const int xo = (g == 0) ? offx8(4 * p)
                         : (g == 1) ? offx8(4 * p + 1)
                         : (g == 2) ? offx8(4 * p + 2)
                                    : offx8(4 * p + 3 > 26 ? 26 : 4 * p + 3);
            bf16x8 af[4];
#pragma unroll
            for (int ct = 0; ct < 4; ++ct)
                af[ct] = *(const bf16x8*)(wn + tap * 4096 + (ct << 10) + wq);
#pragma unroll
            for (int s = 0; s < 4; ++s) {
                bf16x8 bx = *(const bf16x8*)&xs[cur + bsp[s] + xo];
#pragma unroll
                for (int ct = 0; ct < 4; ++ct)
                    acc[ct][s] = __builtin_amdgcn_mfma_f32_16x16x32_bf16(af[ct], bx, acc[ct][s], 0, 0, 0);
            }
        }
        __syncthreads();   // drains staged loads + LDS reads before buffer reuse
    }

    // epilogue: store y (+bias) and accumulate BN stats
    const int row4 = g << 2;
    const float* db = dynb + n * DIMS_;
#pragma unroll
    for (int ct = 0; ct < 4; ++ct) {
        const int cob = ct * 16 + row4;
        float ps[4] = {0.f, 0.f, 0.f, 0.f}, ps2[4] = {0.f, 0.f, 0.f, 0.f};
#pragma unroll
        for (int s = 0; s < 4; ++s) {
            const int ww = (s << 4) + lw;
            size_t base = ((((size_t)n * DIMS_ + cob) * T_ + t) << 12) + ((size_t)(hbase + wid) << 6) + ww;
#pragma unroll
            for (int r = 0; r < 4; ++r) {
                float z = acc[ct][s][r] + db[cob + r];
                y[base + ((size_t)r << 16)] = z;
                ps[r] += z;
                ps2[r] += z * z;
            }
        }
#pragma unroll
        for (int r = 0; r < 4; ++r) {
            float a = ps[r], b = ps2[r];
#pragma unroll
            for (int m = 1; m < 16; m <<= 1) {
                a += __shfl_xor(a, m, 64);
                b += __shfl_xor(b, m, 64);
            }
            if (lw == 0) {
                atomicAdd(&bnred[cob + r], a);
                atomicAdd(&bnred[64 + cob + r], b);
            }
        }
    }
    __syncthreads();
    if (tid < 128) atomicAdd(&sums[tid], bnred[tid]);
}

// ---------------------------------------------------------------------------
// 7-legacy) fallback conv (round-2, staging from fp32 x) + separate bn_stats
__global__ __launch_bounds__(512, 4) void conv3d_mfma(
    const float* __restrict__ x, const unsigned short* __restrict__ wtb,
    const float* __restrict__ dynb, float* __restrict__ y)
{
    __shared__ unsigned short xs[LDSH_];
    const int hb = blockIdx.x, t = blockIdx.y, n = blockIdx.z;
    const int tid = threadIdx.x;
    const int lane = tid & 63, wid = tid >> 6;
    const int lw = lane & 15, g = lane >> 4;
    const int hbase = hb * 8;

    for (int i = tid; i < 360; i += 512) {
        int c6 = i % 6, u = i / 6, side = u & 1, th = u >> 1;
        int tp = th / 10, hp = th % 10;
        int addr = tp * TSTR_ + hp * HSTR_ + (side ? 65 * CS_ : 0) + c6 * 2;
        *(unsigned*)&xs[addr] = 0u;
    }

    f32x4 acc[4][4];
#pragma unroll
    for (int ct = 0; ct < 4; ++ct)
#pragma unroll
        for (int s = 0; s < 4; ++s) acc[ct][s] = (f32x4){0.f, 0.f, 0.f, 0.f};

    int bsp[4];
#pragma unroll
    for (int s = 0; s < 4; ++s) bsp[s] = wid * HSTR_ + ((s << 4) + lw + 1) * CS_;

    const unsigned short* wn = wtb + (size_t)n * (28 * 4096);
    const float* xn = x + (size_t)n * (CIN_ * THW_);
    const int wst = tid & 63, slot = tid >> 6;

    for (int c8 = 0; c8 < 8; ++c8) {
        __syncthreads();
        for (int it = 0; it < 15; ++it) {
            int u = (it << 3) + slot;
            int tp = u / 40, rem = u - tp * 40;
            int hp = rem >> 2, pc = rem & 3;
            int cin = (c8 << 3) + (pc << 1);
            int gt = t + tp - 1, gh = hbase + hp - 1;
            float v0 = 0.f, v1 = 0.f;
            if (((unsigned)gt < 16u) & ((unsigned)gh < 64u)) {
                const float* px = xn + (((size_t)cin << 4) + gt) * HW_ + (gh << 6) + wst;
                v0 = px[0];
                v1 = px[THW_];
            }
            unsigned pr = (unsigned)f2bf(v0) | ((unsigned)f2bf(v1) << 16);
            *(unsigned*)&xs[tp * TSTR_ + hp * HSTR_ + (wst + 1) * CS_ + (pc << 1)] = pr;
        }
        __syncthreads();
        const int wq = (lw << 6) + (c8 << 3);
#pragma unroll
        for (int p = 0; p < 7; ++p) {
            const int tap = 4 * p + g;
            const int xo = (g == 0) ? offx(4 * p)
                         : (g == 1) ? offx(4 * p + 1)
                         : (g == 2) ? offx(4 * p + 2)
                                    : offx(4 * p + 3 > 26 ? 26 : 4 * p + 3);
            bf16x8 af[4];
#pragma unroll
            for (int ct = 0; ct < 4; ++ct)
                af[ct] = *(const bf16x8*)(wn + tap * 4096 + (ct << 10) + wq);
#pragma unroll
            for (int s = 0; s < 4; ++s) {
                union { bf16x8 v; unsigned long long q2[2]; } bx;
                int a0 = bsp[s] + xo;
                bx.q2[0] = *(const unsigned long long*)&xs[a0];
                bx.q2[1] = *(const unsigned long long*)&xs[a0 + 4];
#pragma unroll
                for (int ct = 0; ct < 4; ++ct)
                    acc[ct][s] = __builtin_amdgcn_mfma_f32_16x16x32_bf16(af[ct], bx.v, acc[ct][s], 0, 0, 0);
            }
        }
    }

    const int row4 = (lane >> 4) << 2;
    const float* db = dynb + n * DIMS_;
#pragma unroll
    for (int ct = 0; ct < 4; ++ct) {
        const int co = ct * 16 + row4;
#pragma unroll
        for (int s = 0; s < 4; ++s) {
            const int ww = (s << 4) + lw;
            size_t base = ((((size_t)n * DIMS_ + co) * T_ + t) << 12) + ((size_t)(hbase + wid) << 6) + ww;
#pragma unroll
            for (int r = 0; r < 4; ++r)
                y[base + ((size_t)r << 16)] = acc[ct][s][r] + db[co + r];
        }
    }
}

__global__ void bn_stats(const float* __restrict__ y, float* __restrict__ sums) {
    int nc = blockIdx.x;
    int c = nc & 63;
    const float* p = y + (size_t)nc * THW_;
    float s = 0.f, s2 = 0.f;
    for (int i = threadIdx.x; i < THW_; i += 256) {
        float v = p[i];
        s += v;
        s2 += v * v;
    }
#pragma unroll
    for (int off = 32; off; off >>= 1) {
        s += __shfl_down(s, off, 64);
        s2 += __shfl_down(s2, off, 64);
    }
    __shared__ float sm[8];
    int wid = threadIdx.x >> 6;
    if ((threadIdx.x & 63) == 0) { sm[wid] = s; sm[4 + wid] = s2; }
    __syncthreads();
    if (threadIdx.x == 0) {
        s = sm[0] + sm[1] + sm[2] + sm[3];
        s2 = sm[4] + sm[5] + sm[6] + sm[7];
        atomicAdd(&sums[c], s);
        atomicAdd(&sums[64 + c], s2);
    }
}

// ---------------------------------------------------------------------------
// 9) BN normalize + relu, float4 vectorized, in place
__global__ void bn_norm4(const float* __restrict__ sums, const float* __restrict__ gamma,
                         const float* __restrict__ beta, float* __restrict__ y) {
    size_t idx = (size_t)blockIdx.x * 256 + threadIdx.x;   // over 8,388,608 float4
    int c = (int)((idx >> 14) & 63);
    const float cnt = (float)(N_ * THW_);
    float mean = sums[c] / cnt;
    float var = sums[64 + c] / cnt - mean * mean;
    float sc = gamma[c] * rsqrtf(var + 1e-5f);
    float sh = beta[c] - mean * sc;
    float4 v = ((float4*)y)[idx];
    v.x = fmaxf(fmaf(v.x, sc, sh), 0.f);
    v.y = fmaxf(fmaf(v.y, sc, sh), 0.f);
    v.z = fmaxf(fmaf(v.z, sc, sh), 0.f);
    v.w = fmaxf(fmaf(v.w, sc, sh), 0.f);
    ((float4*)y)[idx] = v;
}

// ---------------------------------------------------------------------------
extern "C" void kernel_launch(void* const* d_in, const int* in_sizes, int n_in,
                              void* d_out, int out_size, void* d_ws, size_t ws_size,
                              hipStream_t stream) {
    const float* x       = (const float*)d_in[0];
    const float* weights = (const float*)d_in[1];
    const float* biases  = (const float*)d_in[2];
    const float* se_w1   = (const float*)d_in[3];
    const float* se_b1   = (const float*)d_in[4];
    const float* se_w2   = (const float*)d_in[5];
    const float* se_b2   = (const float*)d_in[6];
    const float* lin_w   = (const float*)d_in[7];
    const float* lin_b   = (const float*)d_in[8];
    const float* gamma   = (const float*)d_in[9];
    const float* beta    = (const float*)d_in[10];
    const int*   epochs  = (const int*)d_in[11];

    float* out = (float*)d_out;
    float* ws = (float*)d_ws;

    // workspace layout (float slots)
    const size_t STD_OFF  = 0;
    const size_t H1_OFF   = STD_OFF + 2097152;
    const size_t H2_OFF   = H1_OFF + 460800;
    const size_t POOL_OFF = H2_OFF + 802816;
    const size_t PHI_OFF  = POOL_OFF + 256;
    const size_t DYNB_OFF = PHI_OFF + 64;
    const size_t SUMS_OFF = DYNB_OFF + 512;
    const size_t WTB_OFF  = SUMS_OFF + 128;          // bf16 x 917504 = 458752 floats
    const size_t W1T_OFF  = WTB_OFF + 458752;
    const size_t W2T_OFF  = W1T_OFF + 25600;
    const size_t XB_OFF   = W2T_OFF + 12800;         // bf16 x 33554432 = 16777216 floats
    const size_t NEEDED   = (XB_OFF + 16777216) * 4;

    float* std_x  = ws + STD_OFF;
    float* h1     = ws + H1_OFF;
    float* h2     = ws + H2_OFF;
    float* pooled = ws + POOL_OFF;
    float* phi    = ws + PHI_OFF;
    float* dynb   = ws + DYNB_OFF;
    float* sums   = ws + SUMS_OFF;
    unsigned short* wtb = (unsigned short*)(ws + WTB_OFF);
    float* w1t    = ws + W1T_OFF;
    float* w2t    = ws + W2T_OFF;
    unsigned short* xb = (unsigned short*)(ws + XB_OFF);

    const bool fast = (ws_size >= NEEDED);

    hipMemsetAsync(sums, 0, 128 * sizeof(float), stream);

    std_kernel<<<(N_ * CIN_ * HW_) / 256, 256, 0, stream>>>(x, std_x);
    wtrans<<<150, 256, 0, stream>>>(se_w1, se_w2, w1t, w2t);
    if (fast) xb_kernel<<<16384, 256, 0, stream>>>(x, xb);

    se_conv1b<<<dim3(57, 8, 2), 64, 0, stream>>>(std_x, w1t, se_b1, h1);
    se_conv2b<<<dim3(49, 8, 4), 64, 0, stream>>>(h1, w2t, se_b2, h2);
    se_pool<<<N_ * 32, 256, 0, stream>>>(h2, pooled);
    se_head<<<1, 64, 0, stream>>>(pooled, lin_w, lin_b, biases, epochs, phi, dynb);

    dyn_w_bf16<<<dim3(448, 8), 256, 0, stream>>>(weights, phi, wtb);

    if (fast) {
        conv3d_mfma2<<<dim3(8, 16, 8), 512, 0, stream>>>(xb, wtb, dynb, out, sums);
    } else {
        conv3d_mfma<<<dim3(8, 16, 8), 512, 0, stream>>>(x, wtb, dynb, out);
        bn_stats<<<N_ * DIMS_, 256, 0, stream>>>(out, sums);
    }

    bn_norm4<<<32768, 256, 0, stream>>>(sums, gamma, beta, out);
}

// Round 4
// 408.458 us; speedup vs baseline: 16.5197x; 1.2787x over previous
//
#include <hip/hip_runtime.h>
#include <hip/hip_bf16.h>
#include <math.h>

// Problem constants
#define N_   8
#define CIN_ 64
#define DIMS_ 64
#define NW_  8
#define T_   16
#define H_   64
#define W_   64
#define HW_  (H_ * W_)          // 4096
#define THW_ (T_ * HW_)         // 65536

typedef short bf16x8 __attribute__((ext_vector_type(8)));
typedef float f32x16 __attribute__((ext_vector_type(16)));

__device__ __forceinline__ unsigned short f2bf(float f) {
    union { float f; unsigned u; } a; a.f = f;
    unsigned r = a.u + 0x7fffu + ((a.u >> 16) & 1u);   // RNE
    return (unsigned short)(r >> 16);
}

// conv LDS geometry (halfword units): x [3t][10h][66w][8cin], w [28tap][64co][8cin]
#define CS8_ 8
#define HS8_ (66 * CS8_)        // 528
#define TS8_ (10 * HS8_)        // 5280
#define XSH_ (3 * TS8_)         // 15840 hw = 31680 B
#define WLH_ (28 * 64 * 8)      // 14336 hw = 28672 B

__host__ __device__ constexpr int OXc(int tap) {
    int tt = tap > 26 ? 26 : tap;   // tap 27 = zero-weight pad -> any safe addr
    return (tt / 9) * TS8_ + ((tt % 9) / 3) * HS8_ + ((tt % 3) - 1) * CS8_;
}

// ---------------------------------------------------------------------------
// 1) fused: temporal std (ddof=1) + x -> xb bf16 [n][c8][t][h][w][8cin]
//    block 512 = (c 0..7) x (w 0..63); grid (h=64, c8=8, n=8). Reads x ONCE.
__global__ __launch_bounds__(512) void stdxb_kernel(
    const float* __restrict__ x, float* __restrict__ std_x,
    unsigned short* __restrict__ xb)
{
    __shared__ unsigned short xsl[16 * 64 * 8];   // [t][w][c] 16 KB
    const int h = blockIdx.x, c8 = blockIdx.y, n = blockIdx.z;
    const int tid = threadIdx.x;
    const int c = tid >> 6, w = tid & 63;
    const int cin = c8 * 8 + c;
    const float* px = x + (((size_t)(n * 64 + cin)) << 16) + (h << 6) + w;
    float s = 0.f, s2 = 0.f;
#pragma unroll
    for (int t = 0; t < T_; ++t) {
        float v = px[t * HW_];
        s += v;
        s2 += v * v;
        xsl[(t << 9) + (w << 3) + c] = f2bf(v);
    }
    float var = (s2 - s * s * (1.0f / 16.0f)) * (1.0f / 15.0f);
    std_x[(((size_t)(n * 64 + cin)) << 12) + (h << 6) + w] = sqrtf(fmaxf(var, 0.f));
    __syncthreads();
    // write out 1024 int4: j = t*64 + w
    const int4* src = (const int4*)xsl;
    int4* dst = (int4*)(xb + ((size_t)((n * 8 + c8) * 16) << 12) * 8);   // base [n][c8][0][0][0][0]
#pragma unroll
    for (int k = 0; k < 2; ++k) {
        int j = tid + (k << 9);
        int t = j >> 6, ww = j & 63;
        dst[((t << 6) + h) * 64 + ww] = src[j];
    }
}

// ---------------------------------------------------------------------------
// 1c) transpose SE weights
__global__ void wtrans(const float* __restrict__ w1, const float* __restrict__ w2,
                       float* __restrict__ w1t, float* __restrict__ w2t) {
    int i = blockIdx.x * 256 + threadIdx.x;
    if (i < 25600) {
        int k = i / 1600, c = (i / 25) % 64, tap = i % 25;
        w1t[(c * 25 + tap) * 16 + k] = w1[i];
    } else if (i < 38400) {
        int j = i - 25600;
        int o = j / 400, c = (j / 25) % 16, tap = j % 25;
        w2t[(c * 25 + tap) * 32 + o] = w2[j];
    }
}

// ---------------------------------------------------------------------------
// 2) SE conv1: block 256 = 64 ij x 4 c-quarters; 8 k per thread; LDS reduce
__global__ __launch_bounds__(256) void se_conv1c(const float* __restrict__ std_x,
        const float* __restrict__ w1t, const float* __restrict__ b1, float* __restrict__ h1) {
    __shared__ float red[3][64][8];
    const int n = blockIdx.y, ks = blockIdx.z * 8;
    const int iq = threadIdx.x & 63, cq = threadIdx.x >> 6;
    const int ij = blockIdx.x * 64 + iq;
    float acc[8];
#pragma unroll
    for (int q = 0; q < 8; ++q) acc[q] = 0.f;
    if (ij < 3600) {
        int i = ij / 60, j = ij - i * 60;
        const float* xn = std_x + (size_t)n * CIN_ * HW_ + i * W_ + j;
        for (int c = cq * 16; c < cq * 16 + 16; ++c) {
            const float* xc = xn + c * HW_;
            float xv[25];
#pragma unroll
            for (int u = 0; u < 5; ++u)
#pragma unroll
                for (int v = 0; v < 5; ++v) xv[u * 5 + v] = xc[u * W_ + v];
            const float* wc = w1t + c * 400 + ks;
#pragma unroll
            for (int tap = 0; tap < 25; ++tap)
#pragma unroll
                for (int q = 0; q < 8; ++q)
                    acc[q] = fmaf(xv[tap], wc[tap * 16 + q], acc[q]);
        }
    }
    if (cq > 0) {
#pragma unroll
        for (int q = 0; q < 8; ++q) red[cq - 1][iq][q] = acc[q];
    }
    __syncthreads();
    if (cq == 0 && ij < 3600) {
#pragma unroll
        for (int q = 0; q < 8; ++q) {
            float a = acc[q] + red[0][iq][q] + red[1][iq][q] + red[2][iq][q] + b1[ks + q];
            h1[((size_t)(n * 16 + ks + q)) * 3600 + ij] = fmaxf(a, 0.f);
        }
    }
}

// ---------------------------------------------------------------------------
// 3) SE conv2 + fused max-pool (h2 never materialized; atomicMax into pooled)
__global__ __launch_bounds__(256) void se_conv2c(const float* __restrict__ h1,
        const float* __restrict__ w2t, const float* __restrict__ b2,
        unsigned* __restrict__ pooled) {
    __shared__ float red[3][64][8];
    const int n = blockIdx.y, os = blockIdx.z * 8;
    const int iq = threadIdx.x & 63, cq = threadIdx.x >> 6;
    const int ij = blockIdx.x * 64 + iq;   // 0..3135, exact (49*64)
    const int i = ij / 56, j = ij - i * 56;
    float acc[8];
#pragma unroll
    for (int q = 0; q < 8; ++q) acc[q] = 0.f;
    const float* xn = h1 + (size_t)n * 16 * 3600 + i * 60 + j;
    for (int c = cq * 4; c < cq * 4 + 4; ++c) {
        const float* xc = xn + c * 3600;
        float xv[25];
#pragma unroll
        for (int u = 0; u < 5; ++u)
#pragma unroll
            for (int v = 0; v < 5; ++v) xv[u * 5 + v] = xc[u * 60 + v];
        const float* wc = w2t + c * 800 + os;
#pragma unroll
        for (int tap = 0; tap < 25; ++tap)
#pragma unroll
            for (int q = 0; q < 8; ++q)
                acc[q] = fmaf(xv[tap], wc[tap * 32 + q], acc[q]);
    }
    if (cq > 0) {
#pragma unroll
        for (int q = 0; q < 8; ++q) red[cq - 1][iq][q] = acc[q];
    }
    __syncthreads();
    if (cq == 0) {
#pragma unroll
        for (int q = 0; q < 8; ++q) {
            float a = fmaxf(acc[q] + red[0][iq][q] + red[1][iq][q] + red[2][iq][q] + b2[os + q], 0.f);
            // wave-local max first (64 lanes, same q, 64 different ij)
#pragma unroll
            for (int m = 1; m < 64; m <<= 1) a = fmaxf(a, __shfl_xor(a, m, 64));
            if (iq == 0) atomicMax(&pooled[n * 32 + os + q], __float_as_uint(a));
        }
    }
}

// ---------------------------------------------------------------------------
// 5) head: logits -> softmax(phi) -> dyn_b  (pooled holds float bits, relu>=0)
__global__ void se_head(const float* __restrict__ pooled, const float* __restrict__ lin_w,
                        const float* __restrict__ lin_b, const float* __restrict__ biases,
                        const int* __restrict__ epochs, float* __restrict__ phi,
                        float* __restrict__ dyn_b) {
    __shared__ float sphi[NW_][NW_];
    int tid = threadIdx.x;
    int e = epochs[0];
    float tau = (e < 10) ? (30.0f - 2.9f * (float)e) : 1.0f;
    if (tid < 64) {
        int b = tid >> 3, m = tid & 7;
        float acc = lin_b[m];
        for (int k = 0; k < 32; ++k) acc += pooled[b * 32 + k] * lin_w[m * 32 + k];
        sphi[b][m] = acc / tau;
    }
    __syncthreads();
    if (tid < 8) {
        int b = tid;
        float mx = sphi[b][0];
#pragma unroll
        for (int m = 1; m < 8; ++m) mx = fmaxf(mx, sphi[b][m]);
        float ex[8], s = 0.f;
#pragma unroll
        for (int m = 0; m < 8; ++m) { ex[m] = expf(sphi[b][m] - mx); s += ex[m]; }
        float inv = 1.0f / s;
#pragma unroll
        for (int m = 0; m < 8; ++m) { sphi[b][m] = ex[m] * inv; phi[b * 8 + m] = ex[m] * inv; }
    }
    __syncthreads();
    for (int idx = tid; idx < NW_ * DIMS_; idx += blockDim.x) {
        int b = idx >> 6, d = idx & 63;
        float acc = 0.f;
#pragma unroll
        for (int m = 0; m < 8; ++m) acc += sphi[b][m] * biases[m * DIMS_ + d];
        dyn_b[idx] = acc;
    }
}

// ---------------------------------------------------------------------------
// 6) dynamic weights bf16, chunk-major: wtb2[b][c8][28tap][64co][8ci], tap27=0
//    thread -> contiguous dst (coalesced 2B writes)
__global__ void dyn_w_bf16b(const float* __restrict__ weights, const float* __restrict__ phi,
                            unsigned short* __restrict__ wtb2) {
    int g = blockIdx.x * 256 + threadIdx.x;   // 0..114687 per b
    int b = blockIdx.y;
    int c8 = g / 14336, r = g - c8 * 14336;
    int tap = r >> 9, co = (r >> 3) & 63, ci = r & 7;
    int cin = c8 * 8 + ci;
    unsigned short v = 0;
    if (tap < 27) {
        size_t src = ((size_t)(co * 64) + cin) * 27 + tap;
        float acc = 0.f;
#pragma unroll
        for (int m = 0; m < 8; ++m)
            acc += phi[b * 8 + m] * weights[(size_t)m * (64 * 64 * 27) + src];
        v = f2bf(acc);
    }
    wtb2[(size_t)b * 114688 + g] = v;
}

// ---------------------------------------------------------------------------
// 7) conv3d: both operands LDS-staged (single-buffer), 32x32x16 MFMA,
//    fused BN partial stats. Block (hb,t,n), 512 thr = 8 waves, wave = 1 h-row.
__global__ __launch_bounds__(512, 4) void conv3d_mfma3(
    const unsigned short* __restrict__ xb,     // [8][8][16][64][64][8]
    const unsigned short* __restrict__ wtb2,   // [8][8][28][64][8]
    const float* __restrict__ dynb,            // [8][64]
    float* __restrict__ y,                     // [8][64][16][64][64]
    float* __restrict__ sums)                  // [128]
{
    __shared__ __align__(16) unsigned short xs[XSH_];
    __shared__ __align__(16) unsigned short wl[WLH_];
    __shared__ float bnred[128];

    const int hb = blockIdx.x, t = blockIdx.y, n = blockIdx.z;
    const int tid = threadIdx.x;
    const int lane = tid & 63, wid = tid >> 6;
    const int lane31 = lane & 31, tau = lane >> 5;
    const int hbase = hb * 8;

    // zero x buffer (halo rows / w-pads persist as zero) + bnred
    for (int i = tid; i < XSH_ / 8; i += 512)
        *(int4*)&xs[i * 8] = (int4){0, 0, 0, 0};
    if (tid < 128) bnred[tid] = 0.f;

    const unsigned short* xnb = xb + ((size_t)(n * 8) << 16) * 8;     // [c8][t][h][w][8]
    const unsigned short* wnb = wtb2 + (size_t)n * 114688;            // [c8][28][64][8]

    f32x16 acc[2][2];
#pragma unroll
    for (int ci = 0; ci < 2; ++ci)
#pragma unroll
        for (int s = 0; s < 2; ++s)
            acc[ci][s] = (f32x16)(0.f);

    // per-lane constant addresses (halfword units)
    const int aBase = (tau * 64 + lane31) * 8;                 // + p*1024 + ci*256
    const int bsp0 = wid * HS8_ + (1 + lane31) * CS8_;         // + xo
    const int bsp1 = bsp0 + 32 * CS8_;

    for (int c8 = 0; c8 < 8; ++c8) {
        __syncthreads();   // prev compute done (also covers initial zero-fill)
        // ---- stage x: rows wid, wid+8, wid+16, wid+24 (<30)
#pragma unroll
        for (int k = 0; k < 4; ++k) {
            int r = wid + (k << 3);
            if (r < 30) {
                int tp = (r >= 20) ? 2 : (r >= 10 ? 1 : 0);
                int hp = r - tp * 10;
                int gt = t + tp - 1, gh = hbase + hp - 1;
                if (((unsigned)gt < 16u) && ((unsigned)gh < 64u)) {
                    const unsigned short* gp = xnb + (size_t)(((c8 * 16 + gt) * 64 + gh) * 64 + lane) * 8;
                    const unsigned short* lp = &xs[tp * TS8_ + hp * HS8_ + CS8_];
                    __builtin_amdgcn_global_load_lds(
                        (const __attribute__((address_space(1))) void*)gp,
                        (__attribute__((address_space(3))) void*)lp, 16, 0, 0);
                }
            }
        }
        // ---- stage w: taps wid, wid+8, wid+16, wid+24 (<28)
#pragma unroll
        for (int k = 0; k < 4; ++k) {
            int tp = wid + (k << 3);
            if (tp < 28) {
                const unsigned short* gp = wnb + (size_t)(c8 * 14336 + tp * 512 + lane * 8);
                const unsigned short* lp = &wl[tp * 512];
                __builtin_amdgcn_global_load_lds(
                    (const __attribute__((address_space(1))) void*)gp,
                    (__attribute__((address_space(3))) void*)lp, 16, 0, 0);
            }
        }
        __syncthreads();   // vmcnt(0) drain -> staged

        // ---- compute: 14 K-steps of (2 taps x 8 cin)
#pragma unroll
        for (int p = 0; p < 14; ++p) {
            const int xo = tau ? OXc(2 * p + 1) : OXc(2 * p);
            bf16x8 a0 = *(const bf16x8*)&wl[p * 1024 + aBase];
            bf16x8 a1 = *(const bf16x8*)&wl[p * 1024 + aBase + 256];
            bf16x8 b0 = *(const bf16x8*)&xs[bsp0 + xo];
            bf16x8 b1 = *(const bf16x8*)&xs[bsp1 + xo];
            acc[0][0] = __builtin_amdgcn_mfma_f32_32x32x16_bf16(a0, b0, acc[0][0], 0, 0, 0);
            acc[0][1] = __builtin_amdgcn_mfma_f32_32x32x16_bf16(a0, b1, acc[0][1], 0, 0, 0);
            acc[1][0] = __builtin_amdgcn_mfma_f32_32x32x16_bf16(a1, b0, acc[1][0], 0, 0, 0);
            acc[1][1] = __builtin_amdgcn_mfma_f32_32x32x16_bf16(a1, b1, acc[1][1], 0, 0, 0);
        }
    }

    // ---- epilogue: C/D col=lane31(w), row=(r&3)+8*(r>>2)+4*tau (+32*ci)
    const float* db = dynb + n * DIMS_;
    const size_t ybase = (((size_t)n * DIMS_) << 16) + ((size_t)t << 12) + ((size_t)(hbase + wid) << 6);
#pragma unroll
    for (int ci = 0; ci < 2; ++ci) {
#pragma unroll
        for (int r = 0; r < 16; ++r) {
            const int co = 32 * ci + (r & 3) + 8 * (r >> 2) + 4 * tau;
            const float bco = db[co];
            float z0 = acc[ci][0][r] + bco;
            float z1 = acc[ci][1][r] + bco;
            y[ybase + ((size_t)co << 16) + lane31]      = z0;
            y[ybase + ((size_t)co << 16) + 32 + lane31] = z1;
            float ps = z0 + z1, ps2 = z0 * z0 + z1 * z1;
#pragma unroll
            for (int m = 1; m < 32; m <<= 1) {
                ps += __shfl_xor(ps, m, 64);
                ps2 += __shfl_xor(ps2, m, 64);
            }
            if (lane31 == 0) {
                atomicAdd(&bnred[co], ps);
                atomicAdd(&bnred[64 + co], ps2);
            }
        }
    }
    __syncthreads();
    if (tid < 128) atomicAdd(&sums[tid], bnred[tid]);
}

// ---------------------------------------------------------------------------
// 9) BN normalize + relu, float4, in place
__global__ void bn_norm4(const float* __restrict__ sums, const float* __restrict__ gamma,
                         const float* __restrict__ beta, float* __restrict__ y) {
    size_t idx = (size_t)blockIdx.x * 256 + threadIdx.x;
    int c = (int)((idx >> 14) & 63);
    const float cnt = (float)(N_ * THW_);
    float mean = sums[c] / cnt;
    float var = sums[64 + c] / cnt - mean * mean;
    float sc = gamma[c] * rsqrtf(var + 1e-5f);
    float sh = beta[c] - mean * sc;
    float4 v = ((float4*)y)[idx];
    v.x = fmaxf(fmaf(v.x, sc, sh), 0.f);
    v.y = fmaxf(fmaf(v.y, sc, sh), 0.f);
    v.z = fmaxf(fmaf(v.z, sc, sh), 0.f);
    v.w = fmaxf(fmaf(v.w, sc, sh), 0.f);
    ((float4*)y)[idx] = v;
}

// ---------------------------------------------------------------------------
extern "C" void kernel_launch(void* const* d_in, const int* in_sizes, int n_in,
                              void* d_out, int out_size, void* d_ws, size_t ws_size,
                              hipStream_t stream) {
    const float* x       = (const float*)d_in[0];
    const float* weights = (const float*)d_in[1];
    const float* biases  = (const float*)d_in[2];
    const float* se_w1   = (const float*)d_in[3];
    const float* se_b1   = (const float*)d_in[4];
    const float* se_w2   = (const float*)d_in[5];
    const float* se_b2   = (const float*)d_in[6];
    const float* lin_w   = (const float*)d_in[7];
    const float* lin_b   = (const float*)d_in[8];
    const float* gamma   = (const float*)d_in[9];
    const float* beta    = (const float*)d_in[10];
    const int*   epochs  = (const int*)d_in[11];

    float* out = (float*)d_out;
    float* ws = (float*)d_ws;

    // workspace layout (float slots)
    const size_t STD_OFF  = 0;                        // 2,097,152
    const size_t H1_OFF   = STD_OFF + 2097152;        // 460,800
    const size_t SUMS_OFF = H1_OFF + 460800;          // 128
    const size_t POOL_OFF = SUMS_OFF + 128;           // 256
    const size_t PHI_OFF  = POOL_OFF + 256;           // 64
    const size_t DYNB_OFF = PHI_OFF + 64;             // 512
    const size_t WTB_OFF  = DYNB_OFF + 512;           // 458,752 (bf16 x 917,504)
    const size_t W1T_OFF  = WTB_OFF + 458752;         // 25,600
    const size_t W2T_OFF  = W1T_OFF + 25600;          // 12,800
    const size_t XB_OFF   = W2T_OFF + 12800;          // 16,777,216 (bf16 x 33.5M)

    float* std_x  = ws + STD_OFF;
    float* h1     = ws + H1_OFF;
    float* sums   = ws + SUMS_OFF;
    float* pooled = ws + POOL_OFF;
    float* phi    = ws + PHI_OFF;
    float* dynb   = ws + DYNB_OFF;
    unsigned short* wtb2 = (unsigned short*)(ws + WTB_OFF);
    float* w1t    = ws + W1T_OFF;
    float* w2t    = ws + W2T_OFF;
    unsigned short* xb = (unsigned short*)(ws + XB_OFF);

    // zero sums + pooled in one shot (pooled uses uint-max on relu'd >=0 values)
    hipMemsetAsync(sums, 0, (128 + 256) * sizeof(float), stream);

    stdxb_kernel<<<dim3(64, 8, 8), 512, 0, stream>>>(x, std_x, xb);
    wtrans<<<150, 256, 0, stream>>>(se_w1, se_w2, w1t, w2t);

    se_conv1c<<<dim3(57, 8, 2), 256, 0, stream>>>(std_x, w1t, se_b1, h1);
    se_conv2c<<<dim3(49, 8, 4), 256, 0, stream>>>(h1, w2t, se_b2, (unsigned*)pooled);
    se_head<<<1, 64, 0, stream>>>(pooled, lin_w, lin_b, biases, epochs, phi, dynb);

    dyn_w_bf16b<<<dim3(448, 8), 256, 0, stream>>>(weights, phi, wtb2);

    conv3d_mfma3<<<dim3(8, 16, 8), 512, 0, stream>>>(xb, wtb2, dynb, out, sums);

    bn_norm4<<<32768, 256, 0, stream>>>(sums, gamma, beta, out);
}

// Round 5
// 402.078 us; speedup vs baseline: 16.7818x; 1.0159x over previous
//
#include <hip/hip_runtime.h>
#include <hip/hip_bf16.h>
#include <math.h>

// Problem constants
#define N_   8
#define CIN_ 64
#define DIMS_ 64
#define NW_  8
#define T_   16
#define H_   64
#define W_   64
#define HW_  (H_ * W_)          // 4096
#define THW_ (T_ * HW_)         // 65536

typedef short bf16x8 __attribute__((ext_vector_type(8)));
typedef float f32x16 __attribute__((ext_vector_type(16)));

__device__ __forceinline__ unsigned short f2bf(float f) {
    union { float f; unsigned u; } a; a.f = f;
    unsigned r = a.u + 0x7fffu + ((a.u >> 16) & 1u);   // RNE
    return (unsigned short)(r >> 16);
}

// conv LDS geometry (halfword units): x [3t][10h][66w][8cin], w [28tap][64co][8cin]
#define CS8_ 8
#define HS8_ (66 * CS8_)        // 528
#define TS8_ (10 * HS8_)        // 5280
#define XBUF_ (3 * TS8_)        // 15840 hw = 31680 B per x buffer
#define WBUF_ (28 * 64 * 8)     // 14336 hw = 28672 B per w buffer
// dynamic LDS layout (hw): x0 | x1 | w0 | w1 | junk(512) | bnred(128 f32)
#define JUNK_OFF_ (2 * XBUF_ + 2 * WBUF_)          // 60352
#define BNRED_OFF_ (JUNK_OFF_ + 512)               // 60864 hw -> byte 121728
#define DLS_BYTES_ (BNRED_OFF_ * 2 + 128 * 4)      // 122240 B

__host__ __device__ constexpr int OXc(int tap) {
    int tt = tap > 26 ? 26 : tap;   // tap 27 = zero-weight pad -> any safe addr
    return (tt / 9) * TS8_ + ((tt % 9) / 3) * HS8_ + ((tt % 3) - 1) * CS8_;
}

// ---------------------------------------------------------------------------
// 1) fused: temporal std (ddof=1) + x -> xb bf16 [n][c8][t][h][w][8cin]
__global__ __launch_bounds__(512) void stdxb_kernel(
    const float* __restrict__ x, float* __restrict__ std_x,
    unsigned short* __restrict__ xb)
{
    __shared__ unsigned short xsl[16 * 64 * 8];   // [t][w][c] 16 KB
    const int h = blockIdx.x, c8 = blockIdx.y, n = blockIdx.z;
    const int tid = threadIdx.x;
    const int c = tid >> 6, w = tid & 63;
    const int cin = c8 * 8 + c;
    const float* px = x + (((size_t)(n * 64 + cin)) << 16) + (h << 6) + w;
    float s = 0.f, s2 = 0.f;
#pragma unroll
    for (int t = 0; t < T_; ++t) {
        float v = px[t * HW_];
        s += v;
        s2 += v * v;
        xsl[(t << 9) + (w << 3) + c] = f2bf(v);
    }
    float var = (s2 - s * s * (1.0f / 16.0f)) * (1.0f / 15.0f);
    std_x[(((size_t)(n * 64 + cin)) << 12) + (h << 6) + w] = sqrtf(fmaxf(var, 0.f));
    __syncthreads();
    const int4* src = (const int4*)xsl;
    int4* dst = (int4*)(xb + ((size_t)((n * 8 + c8) * 16) << 12) * 8);
#pragma unroll
    for (int k = 0; k < 2; ++k) {
        int j = tid + (k << 9);
        int t = j >> 6, ww = j & 63;
        dst[((t << 6) + h) * 64 + ww] = src[j];
    }
}

// ---------------------------------------------------------------------------
// 1c) transpose SE weights
__global__ void wtrans(const float* __restrict__ w1, const float* __restrict__ w2,
                       float* __restrict__ w1t, float* __restrict__ w2t) {
    int i = blockIdx.x * 256 + threadIdx.x;
    if (i < 25600) {
        int k = i / 1600, c = (i / 25) % 64, tap = i % 25;
        w1t[(c * 25 + tap) * 16 + k] = w1[i];
    } else if (i < 38400) {
        int j = i - 25600;
        int o = j / 400, c = (j / 25) % 16, tap = j % 25;
        w2t[(c * 25 + tap) * 32 + o] = w2[j];
    }
}

// ---------------------------------------------------------------------------
// 2) SE conv1: block 256 = 64 ij x 4 c-quarters; 8 k per thread; LDS reduce
__global__ __launch_bounds__(256) void se_conv1c(const float* __restrict__ std_x,
        const float* __restrict__ w1t, const float* __restrict__ b1, float* __restrict__ h1) {
    __shared__ float red[3][64][8];
    const int n = blockIdx.y, ks = blockIdx.z * 8;
    const int iq = threadIdx.x & 63, cq = threadIdx.x >> 6;
    const int ij = blockIdx.x * 64 + iq;
    float acc[8];
#pragma unroll
    for (int q = 0; q < 8; ++q) acc[q] = 0.f;
    if (ij < 3600) {
        int i = ij / 60, j = ij - i * 60;
        const float* xn = std_x + (size_t)n * CIN_ * HW_ + i * W_ + j;
        for (int c = cq * 16; c < cq * 16 + 16; ++c) {
            const float* xc = xn + c * HW_;
            float xv[25];
#pragma unroll
            for (int u = 0; u < 5; ++u)
#pragma unroll
                for (int v = 0; v < 5; ++v) xv[u * 5 + v] = xc[u * W_ + v];
            const float* wc = w1t + c * 400 + ks;
#pragma unroll
            for (int tap = 0; tap < 25; ++tap)
#pragma unroll
                for (int q = 0; q < 8; ++q)
                    acc[q] = fmaf(xv[tap], wc[tap * 16 + q], acc[q]);
        }
    }
    if (cq > 0) {
#pragma unroll
        for (int q = 0; q < 8; ++q) red[cq - 1][iq][q] = acc[q];
    }
    __syncthreads();
    if (cq == 0 && ij < 3600) {
#pragma unroll
        for (int q = 0; q < 8; ++q) {
            float a = acc[q] + red[0][iq][q] + red[1][iq][q] + red[2][iq][q] + b1[ks + q];
            h1[((size_t)(n * 16 + ks + q)) * 3600 + ij] = fmaxf(a, 0.f);
        }
    }
}

// ---------------------------------------------------------------------------
// 3) SE conv2 + fused max-pool
__global__ __launch_bounds__(256) void se_conv2c(const float* __restrict__ h1,
        const float* __restrict__ w2t, const float* __restrict__ b2,
        unsigned* __restrict__ pooled) {
    __shared__ float red[3][64][8];
    const int n = blockIdx.y, os = blockIdx.z * 8;
    const int iq = threadIdx.x & 63, cq = threadIdx.x >> 6;
    const int ij = blockIdx.x * 64 + iq;   // exact 49*64 = 3136
    const int i = ij / 56, j = ij - i * 56;
    float acc[8];
#pragma unroll
    for (int q = 0; q < 8; ++q) acc[q] = 0.f;
    const float* xn = h1 + (size_t)n * 16 * 3600 + i * 60 + j;
    for (int c = cq * 4; c < cq * 4 + 4; ++c) {
        const float* xc = xn + c * 3600;
        float xv[25];
#pragma unroll
        for (int u = 0; u < 5; ++u)
#pragma unroll
            for (int v = 0; v < 5; ++v) xv[u * 5 + v] = xc[u * 60 + v];
        const float* wc = w2t + c * 800 + os;
#pragma unroll
        for (int tap = 0; tap < 25; ++tap)
#pragma unroll
            for (int q = 0; q < 8; ++q)
                acc[q] = fmaf(xv[tap], wc[tap * 32 + q], acc[q]);
    }
    if (cq > 0) {
#pragma unroll
        for (int q = 0; q < 8; ++q) red[cq - 1][iq][q] = acc[q];
    }
    __syncthreads();
    if (cq == 0) {
#pragma unroll
        for (int q = 0; q < 8; ++q) {
            float a = fmaxf(acc[q] + red[0][iq][q] + red[1][iq][q] + red[2][iq][q] + b2[os + q], 0.f);
#pragma unroll
            for (int m = 1; m < 64; m <<= 1) a = fmaxf(a, __shfl_xor(a, m, 64));
            if (iq == 0) atomicMax(&pooled[n * 32 + os + q], __float_as_uint(a));
        }
    }
}

// ---------------------------------------------------------------------------
// 5) head: logits -> softmax(phi) -> dyn_b
__global__ void se_head(const float* __restrict__ pooled, const float* __restrict__ lin_w,
                        const float* __restrict__ lin_b, const float* __restrict__ biases,
                        const int* __restrict__ epochs, float* __restrict__ phi,
                        float* __restrict__ dyn_b) {
    __shared__ float sphi[NW_][NW_];
    int tid = threadIdx.x;
    int e = epochs[0];
    float tau = (e < 10) ? (30.0f - 2.9f * (float)e) : 1.0f;
    if (tid < 64) {
        int b = tid >> 3, m = tid & 7;
        float acc = lin_b[m];
        for (int k = 0; k < 32; ++k) acc += pooled[b * 32 + k] * lin_w[m * 32 + k];
        sphi[b][m] = acc / tau;
    }
    __syncthreads();
    if (tid < 8) {
        int b = tid;
        float mx = sphi[b][0];
#pragma unroll
        for (int m = 1; m < 8; ++m) mx = fmaxf(mx, sphi[b][m]);
        float ex[8], s = 0.f;
#pragma unroll
        for (int m = 0; m < 8; ++m) { ex[m] = expf(sphi[b][m] - mx); s += ex[m]; }
        float inv = 1.0f / s;
#pragma unroll
        for (int m = 0; m < 8; ++m) { sphi[b][m] = ex[m] * inv; phi[b * 8 + m] = ex[m] * inv; }
    }
    __syncthreads();
    for (int idx = tid; idx < NW_ * DIMS_; idx += blockDim.x) {
        int b = idx >> 6, d = idx & 63;
        float acc = 0.f;
#pragma unroll
        for (int m = 0; m < 8; ++m) acc += sphi[b][m] * biases[m * DIMS_ + d];
        dyn_b[idx] = acc;
    }
}

// ---------------------------------------------------------------------------
// 6) dynamic weights, ONE pass over weights (all 8 batches per thread).
//    src coalesced; dst wtb2[b][c8][tap][co][8ci] (tap27 slots pre-zeroed by memset)
__global__ void dyn_w_all(const float* __restrict__ weights, const float* __restrict__ phi,
                          unsigned short* __restrict__ wtb2) {
    __shared__ float sphi[64];
    int tid = threadIdx.x;
    if (tid < 64) sphi[tid] = phi[tid];
    __syncthreads();
    int f = blockIdx.x * 256 + tid;   // 0..110591 = co*1728 + cin*27 + tap
    if (f >= 110592) return;
    int tap = f % 27, cin = (f / 27) & 63, co = f / 1728;
    float wv[8];
#pragma unroll
    for (int m = 0; m < 8; ++m) wv[m] = weights[(size_t)m * 110592 + f];
    size_t dbase = (size_t)(cin >> 3) * 14336 + tap * 512 + co * 8 + (cin & 7);
#pragma unroll
    for (int b = 0; b < 8; ++b) {
        float acc = 0.f;
#pragma unroll
        for (int m = 0; m < 8; ++m) acc += sphi[b * 8 + m] * wv[m];
        wtb2[(size_t)b * 114688 + dbase] = f2bf(acc);
    }
}

// ---------------------------------------------------------------------------
// 7) conv3d: double-buffered x AND w staging (dynamic LDS 122 KB), counted
//    vmcnt + raw barriers (loads stay in flight across barriers), 32x32x16
//    MFMA, fused BN partial stats. Block (hb,t,n), 512 thr = 8 waves.
extern __shared__ unsigned short dls[];

__global__ __launch_bounds__(512) void conv3d_mfma4(
    const unsigned short* __restrict__ xb,     // [8][8][16][64][64][8]
    const unsigned short* __restrict__ wtb2,   // [8][8][28][64][8]
    const float* __restrict__ dynb,            // [8][64]
    float* __restrict__ y,                     // [8][64][16][64][64]
    float* __restrict__ sums)                  // [128]
{
    const int hb = blockIdx.x, t = blockIdx.y, n = blockIdx.z;
    const int tid = threadIdx.x;
    const int lane = tid & 63, wid = tid >> 6;
    const int lane31 = lane & 31, tau = lane >> 5;
    const int hbase = hb * 8;

    unsigned short* junk = dls + JUNK_OFF_;
    float* bnred = (float*)(dls + BNRED_OFF_);

    // zero both x buffers (halo rows / w-pads stay zero forever) + bnred
    for (int i = tid; i < (2 * XBUF_) / 8; i += 512)
        *(int4*)&dls[i * 8] = (int4){0, 0, 0, 0};
    if (tid < 128) bnred[tid] = 0.f;
    __syncthreads();   // nothing outstanding yet; plain barrier fine

    const unsigned short* xnb = xb + (size_t)n * 4194304;     // [c8][t][h][w][8]
    const unsigned short* wnb = wtb2 + (size_t)n * 114688;    // [c8][28][64][8]

    // stage chunk c8 into buffer parity pb: exactly 8 VMEM ops per thread
    auto STAGE = [&](int c8, int pb) {
        unsigned short* xbuf = dls + pb * XBUF_;
        unsigned short* wbuf = dls + 2 * XBUF_ + pb * WBUF_;
        // w: taps wid, wid+8, wid+16, wid+24 (tp>=28 -> junk)
#pragma unroll
        for (int k = 0; k < 4; ++k) {
            int tp = wid + (k << 3);
            bool ok = tp < 28;
            const unsigned short* gp = wnb + ((size_t)c8 * 14336 + (ok ? tp * 512 : 0) + lane * 8);
            unsigned short* lp = ok ? (wbuf + tp * 512) : junk;
            __builtin_amdgcn_global_load_lds(
                (const __attribute__((address_space(1))) void*)gp,
                (__attribute__((address_space(3))) void*)lp, 16, 0, 0);
        }
        // x: rows wid, wid+8, wid+16, wid+24 (r>=30 or halo-OOB -> junk)
#pragma unroll
        for (int k = 0; k < 4; ++k) {
            int r = wid + (k << 3);
            int tp = (r >= 20) ? 2 : (r >= 10 ? 1 : 0);
            int hp = r - tp * 10;
            int gt = t + tp - 1, gh = hbase + hp - 1;
            bool ok = (r < 30) && ((unsigned)gt < 16u) && ((unsigned)gh < 64u);
            const unsigned short* gp = xnb +
                (ok ? (size_t)(((c8 * 16 + gt) * 64 + gh) * 64 + lane) * 8 : (size_t)lane * 8);
            unsigned short* lp = ok ? (xbuf + tp * TS8_ + hp * HS8_ + CS8_) : junk;
            __builtin_amdgcn_global_load_lds(
                (const __attribute__((address_space(1))) void*)gp,
                (__attribute__((address_space(3))) void*)lp, 16, 0, 0);
        }
    };

    f32x16 acc[2][2];
#pragma unroll
    for (int ci = 0; ci < 2; ++ci)
#pragma unroll
        for (int s = 0; s < 2; ++s)
            acc[ci][s] = (f32x16)(0.f);

    const int aBase = (tau * 64 + lane31) * 8;
    const int bsp0 = wid * HS8_ + (1 + lane31) * CS8_;
    const int bsp1 = bsp0 + 32 * CS8_;

    STAGE(0, 0);

    for (int c8 = 0; c8 < 8; ++c8) {
        if (c8 < 7) {
            STAGE(c8 + 1, (c8 + 1) & 1);                       // prefetch (8 ops)
            asm volatile("s_waitcnt vmcnt(8)" ::: "memory");   // wait chunk c8 only
        } else {
            asm volatile("s_waitcnt vmcnt(0)" ::: "memory");
        }
        __builtin_amdgcn_s_barrier();          // chunk c8 visible to all waves
        __builtin_amdgcn_sched_barrier(0);

        const unsigned short* xsb = dls + (c8 & 1) * XBUF_;
        const unsigned short* wlb = dls + 2 * XBUF_ + (c8 & 1) * WBUF_;
#pragma unroll
        for (int p = 0; p < 14; ++p) {
            const int xo = tau ? OXc(2 * p + 1) : OXc(2 * p);
            bf16x8 a0 = *(const bf16x8*)&wlb[p * 1024 + aBase];
            bf16x8 a1 = *(const bf16x8*)&wlb[p * 1024 + aBase + 256];
            bf16x8 b0 = *(const bf16x8*)&xsb[bsp0 + xo];
            bf16x8 b1 = *(const bf16x8*)&xsb[bsp1 + xo];
            acc[0][0] = __builtin_amdgcn_mfma_f32_32x32x16_bf16(a0, b0, acc[0][0], 0, 0, 0);
            acc[0][1] = __builtin_amdgcn_mfma_f32_32x32x16_bf16(a0, b1, acc[0][1], 0, 0, 0);
            acc[1][0] = __builtin_amdgcn_mfma_f32_32x32x16_bf16(a1, b0, acc[1][0], 0, 0, 0);
            acc[1][1] = __builtin_amdgcn_mfma_f32_32x32x16_bf16(a1, b1, acc[1][1], 0, 0, 0);
        }
        __builtin_amdgcn_s_barrier();          // all waves done reading this parity
    }

    // ---- epilogue: C/D col=lane31(w), row=(r&3)+8*(r>>2)+4*tau (+32*ci)
    const float* db = dynb + n * DIMS_;
    const size_t ybase = (((size_t)n * DIMS_) << 16) + ((size_t)t << 12) + ((size_t)(hbase + wid) << 6);
#pragma unroll
    for (int ci = 0; ci < 2; ++ci) {
#pragma unroll
        for (int r = 0; r < 16; ++r) {
            const int co = 32 * ci + (r & 3) + 8 * (r >> 2) + 4 * tau;
            const float bco = db[co];
            float z0 = acc[ci][0][r] + bco;
            float z1 = acc[ci][1][r] + bco;
            y[ybase + ((size_t)co << 16) + lane31]      = z0;
            y[ybase + ((size_t)co << 16) + 32 + lane31] = z1;
            float ps = z0 + z1, ps2 = z0 * z0 + z1 * z1;
#pragma unroll
            for (int m = 1; m < 32; m <<= 1) {
                ps += __shfl_xor(ps, m, 64);
                ps2 += __shfl_xor(ps2, m, 64);
            }
            if (lane31 == 0) {
                atomicAdd(&bnred[co], ps);
                atomicAdd(&bnred[64 + co], ps2);
            }
        }
    }
    __syncthreads();
    if (tid < 128) atomicAdd(&sums[tid], bnred[tid]);
}

// ---------------------------------------------------------------------------
// 9) BN normalize + relu, float4, grid-stride, in place
__global__ void bn_norm4(const float* __restrict__ sums, const float* __restrict__ gamma,
                         const float* __restrict__ beta, float* __restrict__ y) {
    const float cnt = (float)(N_ * THW_);
    for (size_t idx = (size_t)blockIdx.x * 256 + threadIdx.x; idx < 8388608;
         idx += (size_t)4096 * 256) {
        int c = (int)((idx >> 14) & 63);
        float mean = sums[c] / cnt;
        float var = sums[64 + c] / cnt - mean * mean;
        float sc = gamma[c] * rsqrtf(var + 1e-5f);
        float sh = beta[c] - mean * sc;
        float4 v = ((float4*)y)[idx];
        v.x = fmaxf(fmaf(v.x, sc, sh), 0.f);
        v.y = fmaxf(fmaf(v.y, sc, sh), 0.f);
        v.z = fmaxf(fmaf(v.z, sc, sh), 0.f);
        v.w = fmaxf(fmaf(v.w, sc, sh), 0.f);
        ((float4*)y)[idx] = v;
    }
}

// ---------------------------------------------------------------------------
extern "C" void kernel_launch(void* const* d_in, const int* in_sizes, int n_in,
                              void* d_out, int out_size, void* d_ws, size_t ws_size,
                              hipStream_t stream) {
    const float* x       = (const float*)d_in[0];
    const float* weights = (const float*)d_in[1];
    const float* biases  = (const float*)d_in[2];
    const float* se_w1   = (const float*)d_in[3];
    const float* se_b1   = (const float*)d_in[4];
    const float* se_w2   = (const float*)d_in[5];
    const float* se_b2   = (const float*)d_in[6];
    const float* lin_w   = (const float*)d_in[7];
    const float* lin_b   = (const float*)d_in[8];
    const float* gamma   = (const float*)d_in[9];
    const float* beta    = (const float*)d_in[10];
    const int*   epochs  = (const int*)d_in[11];

    float* out = (float*)d_out;
    float* ws = (float*)d_ws;

    // workspace layout (float slots)
    const size_t STD_OFF  = 0;                        // 2,097,152
    const size_t H1_OFF   = STD_OFF + 2097152;        // 460,800
    const size_t SUMS_OFF = H1_OFF + 460800;          // 128
    const size_t POOL_OFF = SUMS_OFF + 128;           // 256
    const size_t PHI_OFF  = POOL_OFF + 256;           // 64
    const size_t DYNB_OFF = PHI_OFF + 64;             // 512
    const size_t WTB_OFF  = DYNB_OFF + 512;           // 458,752 (bf16 x 917,504)
    const size_t W1T_OFF  = WTB_OFF + 458752;         // 25,600
    const size_t W2T_OFF  = W1T_OFF + 25600;          // 12,800
    const size_t XB_OFF   = W2T_OFF + 12800;          // 16,777,216 (bf16 x 33.5M)

    float* std_x  = ws + STD_OFF;
    float* h1     = ws + H1_OFF;
    float* sums   = ws + SUMS_OFF;
    float* pooled = ws + POOL_OFF;
    float* phi    = ws + PHI_OFF;
    float* dynb   = ws + DYNB_OFF;
    unsigned short* wtb2 = (unsigned short*)(ws + WTB_OFF);
    float* w1t    = ws + W1T_OFF;
    float* w2t    = ws + W2T_OFF;
    unsigned short* xb = (unsigned short*)(ws + XB_OFF);

    // allow >64KB dynamic LDS for the conv kernel (idempotent, capture-safe)
    hipFuncSetAttribute((const void*)conv3d_mfma4,
                        hipFuncAttributeMaxDynamicSharedMemorySize, DLS_BYTES_);

    // zero sums + pooled; zero wtb2 (tap-27 slots must be zero)
    hipMemsetAsync(sums, 0, (128 + 256) * sizeof(float), stream);
    hipMemsetAsync(wtb2, 0, (size_t)8 * 114688 * sizeof(unsigned short), stream);

    stdxb_kernel<<<dim3(64, 8, 8), 512, 0, stream>>>(x, std_x, xb);
    wtrans<<<150, 256, 0, stream>>>(se_w1, se_w2, w1t, w2t);

    se_conv1c<<<dim3(57, 8, 2), 256, 0, stream>>>(std_x, w1t, se_b1, h1);
    se_conv2c<<<dim3(49, 8, 4), 256, 0, stream>>>(h1, w2t, se_b2, (unsigned*)pooled);
    se_head<<<1, 64, 0, stream>>>(pooled, lin_w, lin_b, biases, epochs, phi, dynb);

    dyn_w_all<<<432, 256, 0, stream>>>(weights, phi, wtb2);

    conv3d_mfma4<<<dim3(8, 16, 8), 512, DLS_BYTES_, stream>>>(xb, wtb2, dynb, out, sums);

    bn_norm4<<<4096, 256, 0, stream>>>(sums, gamma, beta, out);
}

// Round 6
// 372.218 us; speedup vs baseline: 18.1280x; 1.0802x over previous
//
#include <hip/hip_runtime.h>
#include <hip/hip_bf16.h>
#include <math.h>

// Problem constants
#define N_   8
#define CIN_ 64
#define DIMS_ 64
#define NW_  8
#define T_   16
#define H_   64
#define W_   64
#define HW_  (H_ * W_)          // 4096
#define THW_ (T_ * HW_)         // 65536

typedef short bf16x8 __attribute__((ext_vector_type(8)));
typedef float f32x16 __attribute__((ext_vector_type(16)));

__device__ __forceinline__ unsigned short f2bf(float f) {
    union { float f; unsigned u; } a; a.f = f;
    unsigned r = a.u + 0x7fffu + ((a.u >> 16) & 1u);   // RNE
    return (unsigned short)(r >> 16);
}

// conv LDS geometry (halfword units): x [3t][10h][66w][8cin], w [28tap][64co][8cin]
#define CS8_ 8
#define HS8_ (66 * CS8_)        // 528
#define TS8_ (10 * HS8_)        // 5280
#define XSH_ (3 * TS8_)         // 15840 hw = 31680 B
#define WLH_ (28 * 64 * 8)      // 14336 hw = 28672 B

__host__ __device__ constexpr int OXc(int tap) {
    int tt = tap > 26 ? 26 : tap;   // tap 27 = zero-weight pad -> any safe addr
    return (tt / 9) * TS8_ + ((tt % 9) / 3) * HS8_ + ((tt % 3) - 1) * CS8_;
}

// ---------------------------------------------------------------------------
// 1) fused: temporal std (ddof=1) + x -> xb bf16 [n][c8][t][h][w][8cin]
//    block (0,0,0) additionally zeroes sums[128] and pooled[256].
__global__ __launch_bounds__(512) void stdxb_kernel(
    const float* __restrict__ x, float* __restrict__ std_x,
    unsigned short* __restrict__ xb, float* __restrict__ sums,
    unsigned* __restrict__ pooled)
{
    __shared__ unsigned short xsl[16 * 64 * 8];   // [t][w][c] 16 KB
    const int h = blockIdx.x, c8 = blockIdx.y, n = blockIdx.z;
    const int tid = threadIdx.x;
    if ((blockIdx.x | blockIdx.y | blockIdx.z) == 0) {
        if (tid < 128) sums[tid] = 0.f;
        else if (tid < 384) pooled[tid - 128] = 0u;
    }
    const int c = tid >> 6, w = tid & 63;
    const int cin = c8 * 8 + c;
    const float* px = x + (((size_t)(n * 64 + cin)) << 16) + (h << 6) + w;
    float s = 0.f, s2 = 0.f;
#pragma unroll
    for (int t = 0; t < T_; ++t) {
        float v = px[t * HW_];
        s += v;
        s2 += v * v;
        xsl[(t << 9) + (w << 3) + c] = f2bf(v);
    }
    float var = (s2 - s * s * (1.0f / 16.0f)) * (1.0f / 15.0f);
    std_x[(((size_t)(n * 64 + cin)) << 12) + (h << 6) + w] = sqrtf(fmaxf(var, 0.f));
    __syncthreads();
    const int4* src = (const int4*)xsl;
    int4* dst = (int4*)(xb + ((size_t)((n * 8 + c8) * 16) << 12) * 8);
#pragma unroll
    for (int k = 0; k < 2; ++k) {
        int j = tid + (k << 9);
        int t = j >> 6, ww = j & 63;
        dst[((t << 6) + h) * 64 + ww] = src[j];
    }
}

// ---------------------------------------------------------------------------
// 1c) transpose SE weights
__global__ void wtrans(const float* __restrict__ w1, const float* __restrict__ w2,
                       float* __restrict__ w1t, float* __restrict__ w2t) {
    int i = blockIdx.x * 256 + threadIdx.x;
    if (i < 25600) {
        int k = i / 1600, c = (i / 25) % 64, tap = i % 25;
        w1t[(c * 25 + tap) * 16 + k] = w1[i];
    } else if (i < 38400) {
        int j = i - 25600;
        int o = j / 400, c = (j / 25) % 16, tap = j % 25;
        w2t[(c * 25 + tap) * 32 + o] = w2[j];
    }
}

// ---------------------------------------------------------------------------
// 2) SE conv1: block 256 = 64 ij x 4 c-quarters; 8 k per thread; LDS reduce
__global__ __launch_bounds__(256) void se_conv1c(const float* __restrict__ std_x,
        const float* __restrict__ w1t, const float* __restrict__ b1, float* __restrict__ h1) {
    __shared__ float red[3][64][8];
    const int n = blockIdx.y, ks = blockIdx.z * 8;
    const int iq = threadIdx.x & 63, cq = threadIdx.x >> 6;
    const int ij = blockIdx.x * 64 + iq;
    float acc[8];
#pragma unroll
    for (int q = 0; q < 8; ++q) acc[q] = 0.f;
    if (ij < 3600) {
        int i = ij / 60, j = ij - i * 60;
        const float* xn = std_x + (size_t)n * CIN_ * HW_ + i * W_ + j;
        for (int c = cq * 16; c < cq * 16 + 16; ++c) {
            const float* xc = xn + c * HW_;
            float xv[25];
#pragma unroll
            for (int u = 0; u < 5; ++u)
#pragma unroll
                for (int v = 0; v < 5; ++v) xv[u * 5 + v] = xc[u * W_ + v];
            const float* wc = w1t + c * 400 + ks;
#pragma unroll
            for (int tap = 0; tap < 25; ++tap)
#pragma unroll
                for (int q = 0; q < 8; ++q)
                    acc[q] = fmaf(xv[tap], wc[tap * 16 + q], acc[q]);
        }
    }
    if (cq > 0) {
#pragma unroll
        for (int q = 0; q < 8; ++q) red[cq - 1][iq][q] = acc[q];
    }
    __syncthreads();
    if (cq == 0 && ij < 3600) {
#pragma unroll
        for (int q = 0; q < 8; ++q) {
            float a = acc[q] + red[0][iq][q] + red[1][iq][q] + red[2][iq][q] + b1[ks + q];
            h1[((size_t)(n * 16 + ks + q)) * 3600 + ij] = fmaxf(a, 0.f);
        }
    }
}

// ---------------------------------------------------------------------------
// 3) SE conv2 + fused max-pool
__global__ __launch_bounds__(256) void se_conv2c(const float* __restrict__ h1,
        const float* __restrict__ w2t, const float* __restrict__ b2,
        unsigned* __restrict__ pooled) {
    __shared__ float red[3][64][8];
    const int n = blockIdx.y, os = blockIdx.z * 8;
    const int iq = threadIdx.x & 63, cq = threadIdx.x >> 6;
    const int ij = blockIdx.x * 64 + iq;   // exact 49*64 = 3136
    const int i = ij / 56, j = ij - i * 56;
    float acc[8];
#pragma unroll
    for (int q = 0; q < 8; ++q) acc[q] = 0.f;
    const float* xn = h1 + (size_t)n * 16 * 3600 + i * 60 + j;
    for (int c = cq * 4; c < cq * 4 + 4; ++c) {
        const float* xc = xn + c * 3600;
        float xv[25];
#pragma unroll
        for (int u = 0; u < 5; ++u)
#pragma unroll
            for (int v = 0; v < 5; ++v) xv[u * 5 + v] = xc[u * 60 + v];
        const float* wc = w2t + c * 800 + os;
#pragma unroll
        for (int tap = 0; tap < 25; ++tap)
#pragma unroll
            for (int q = 0; q < 8; ++q)
                acc[q] = fmaf(xv[tap], wc[tap * 32 + q], acc[q]);
    }
    if (cq > 0) {
#pragma unroll
        for (int q = 0; q < 8; ++q) red[cq - 1][iq][q] = acc[q];
    }
    __syncthreads();
    if (cq == 0) {
#pragma unroll
        for (int q = 0; q < 8; ++q) {
            float a = fmaxf(acc[q] + red[0][iq][q] + red[1][iq][q] + red[2][iq][q] + b2[os + q], 0.f);
#pragma unroll
            for (int m = 1; m < 64; m <<= 1) a = fmaxf(a, __shfl_xor(a, m, 64));
            if (iq == 0) atomicMax(&pooled[n * 32 + os + q], __float_as_uint(a));
        }
    }
}

// ---------------------------------------------------------------------------
// 6) dyn weights + head fused. Every block recomputes softmax(phi) in LDS
//    (trivial); block 0 writes dyn_b; first 64 blocks zero the tap-27 slots.
//    dst wtb2[b][c8][tap][co][8ci]
__global__ __launch_bounds__(256) void dyn_w_head(
    const float* __restrict__ weights, const float* __restrict__ pooled,
    const float* __restrict__ lin_w, const float* __restrict__ lin_b,
    const float* __restrict__ biases, const int* __restrict__ epochs,
    unsigned short* __restrict__ wtb2, float* __restrict__ dyn_b) {
    __shared__ float slog[8][8];
    __shared__ float sphi[64];
    const int tid = threadIdx.x;
    const int e = epochs[0];
    const float tau = (e < 10) ? (30.0f - 2.9f * (float)e) : 1.0f;
    if (tid < 64) {
        int b = tid >> 3, m = tid & 7;
        float acc = lin_b[m];
#pragma unroll
        for (int k = 0; k < 32; ++k) acc += pooled[b * 32 + k] * lin_w[m * 32 + k];
        slog[b][m] = acc / tau;
    }
    __syncthreads();
    if (tid < 8) {
        float mx = slog[tid][0];
#pragma unroll
        for (int m = 1; m < 8; ++m) mx = fmaxf(mx, slog[tid][m]);
        float ex[8], ssum = 0.f;
#pragma unroll
        for (int m = 0; m < 8; ++m) { ex[m] = expf(slog[tid][m] - mx); ssum += ex[m]; }
        float inv = 1.0f / ssum;
#pragma unroll
        for (int m = 0; m < 8; ++m) sphi[tid * 8 + m] = ex[m] * inv;
    }
    __syncthreads();
    // tap-27 zero-fill (64 regions of 512 hw)
    if (blockIdx.x < 64) {
        int b = blockIdx.x >> 3, c8 = blockIdx.x & 7;
        unsigned* dst = (unsigned*)(wtb2 + (size_t)b * 114688 + (size_t)(c8 * 28 + 27) * 512);
        dst[tid] = 0u;   // 256 u32 = 512 hw
    }
    if (blockIdx.x == 0) {
#pragma unroll
        for (int idx = tid; idx < 512; idx += 256) {
            int b = idx >> 6, d = idx & 63;
            float a = 0.f;
#pragma unroll
            for (int m = 0; m < 8; ++m) a += sphi[b * 8 + m] * biases[m * DIMS_ + d];
            dyn_b[idx] = a;
        }
    }
    int f = blockIdx.x * 256 + tid;   // 0..110591 = co*1728 + cin*27 + tap
    if (f >= 110592) return;
    int tap = f % 27, cin = (f / 27) & 63, co = f / 1728;
    float wv[8];
#pragma unroll
    for (int m = 0; m < 8; ++m) wv[m] = weights[(size_t)m * 110592 + f];
    size_t dbase = (size_t)(cin >> 3) * 14336 + tap * 512 + co * 8 + (cin & 7);
#pragma unroll
    for (int b = 0; b < 8; ++b) {
        float acc = 0.f;
#pragma unroll
        for (int m = 0; m < 8; ++m) acc += sphi[b * 8 + m] * wv[m];
        wtb2[(size_t)b * 114688 + dbase] = f2bf(acc);
    }
}

// ---------------------------------------------------------------------------
// 7) conv3d: 256 thr = 4 waves, each wave 2 h-rows -> 2x4 outer product
//    (reads/MFMA 0.75 vs 1.0). Single-buffer LDS (60.9 KB, 2 blocks/CU),
//    round-4 stage/compute rhythm, fused BN partial stats.
__global__ __launch_bounds__(256, 2) void conv3d_mfma5(
    const unsigned short* __restrict__ xb,     // [8][8][16][64][64][8]
    const unsigned short* __restrict__ wtb2,   // [8][8][28][64][8]
    const float* __restrict__ dynb,            // [8][64]
    float* __restrict__ y,                     // [8][64][16][64][64]
    float* __restrict__ sums)                  // [128]
{
    __shared__ __align__(16) unsigned short xs[XSH_];
    __shared__ __align__(16) unsigned short wl[WLH_];
    __shared__ float bnred[128];

    const int hb = blockIdx.x, t = blockIdx.y, n = blockIdx.z;
    const int tid = threadIdx.x;
    const int lane = tid & 63, wid = tid >> 6;     // 4 waves
    const int lane31 = lane & 31, tau = lane >> 5;
    const int hbase = hb * 8;

    // zero x buffer (halo rows / w-pads stay zero all chunks) + bnred
    for (int i = tid; i < XSH_ / 8; i += 256)
        *(int4*)&xs[i * 8] = (int4){0, 0, 0, 0};
    if (tid < 128) bnred[tid] = 0.f;

    const unsigned short* xnb = xb + (size_t)n * 4194304;     // [c8][t][h][w][8]
    const unsigned short* wnb = wtb2 + (size_t)n * 114688;    // [c8][28][64][8]

    f32x16 acc[2][4];
#pragma unroll
    for (int ci = 0; ci < 2; ++ci)
#pragma unroll
        for (int s = 0; s < 4; ++s)
            acc[ci][s] = (f32x16)(0.f);

    const int aBase = tau * 512 + lane31 * 8;
    int bsp[4];
#pragma unroll
    for (int s = 0; s < 4; ++s)
        bsp[s] = (2 * wid + (s >> 1)) * HS8_ + (1 + (s & 1) * 32 + lane31) * CS8_;

    for (int c8 = 0; c8 < 8; ++c8) {
        __syncthreads();   // waves done reading previous chunk (also after zero-fill)
        // ---- stage w: taps wid+4k, k=0..6 (exactly 28)
#pragma unroll
        for (int k = 0; k < 7; ++k) {
            int tp = wid + (k << 2);
            const unsigned short* gp = wnb + ((size_t)c8 * 14336 + tp * 512 + lane * 8);
            const unsigned short* lp = &wl[tp * 512];
            __builtin_amdgcn_global_load_lds(
                (const __attribute__((address_space(1))) void*)gp,
                (__attribute__((address_space(3))) void*)lp, 16, 0, 0);
        }
        // ---- stage x: rows wid+4k, k=0..7 (30 rows used)
#pragma unroll
        for (int k = 0; k < 8; ++k) {
            int r = wid + (k << 2);
            if (r < 30) {
                int tp = (r >= 20) ? 2 : (r >= 10 ? 1 : 0);
                int hp = r - tp * 10;
                int gt = t + tp - 1, gh = hbase + hp - 1;
                if (((unsigned)gt < 16u) && ((unsigned)gh < 64u)) {
                    const unsigned short* gp = xnb + (size_t)(((c8 * 16 + gt) * 64 + gh) * 64 + lane) * 8;
                    const unsigned short* lp = &xs[tp * TS8_ + hp * HS8_ + CS8_];
                    __builtin_amdgcn_global_load_lds(
                        (const __attribute__((address_space(1))) void*)gp,
                        (__attribute__((address_space(3))) void*)lp, 16, 0, 0);
                }
            }
        }
        __syncthreads();   // vmcnt(0) drain -> chunk staged

        // ---- compute: 14 K-steps of (2 taps x 8 cin); 6 reads -> 8 MFMAs
#pragma unroll
        for (int p = 0; p < 14; ++p) {
            const int xo = tau ? OXc(2 * p + 1) : OXc(2 * p);
            bf16x8 a0 = *(const bf16x8*)&wl[p * 1024 + aBase];
            bf16x8 a1 = *(const bf16x8*)&wl[p * 1024 + aBase + 256];
            bf16x8 b0 = *(const bf16x8*)&xs[bsp[0] + xo];
            bf16x8 b1 = *(const bf16x8*)&xs[bsp[1] + xo];
            bf16x8 b2 = *(const bf16x8*)&xs[bsp[2] + xo];
            bf16x8 b3 = *(const bf16x8*)&xs[bsp[3] + xo];
            acc[0][0] = __builtin_amdgcn_mfma_f32_32x32x16_bf16(a0, b0, acc[0][0], 0, 0, 0);
            acc[0][1] = __builtin_amdgcn_mfma_f32_32x32x16_bf16(a0, b1, acc[0][1], 0, 0, 0);
            acc[0][2] = __builtin_amdgcn_mfma_f32_32x32x16_bf16(a0, b2, acc[0][2], 0, 0, 0);
            acc[0][3] = __builtin_amdgcn_mfma_f32_32x32x16_bf16(a0, b3, acc[0][3], 0, 0, 0);
            acc[1][0] = __builtin_amdgcn_mfma_f32_32x32x16_bf16(a1, b0, acc[1][0], 0, 0, 0);
            acc[1][1] = __builtin_amdgcn_mfma_f32_32x32x16_bf16(a1, b1, acc[1][1], 0, 0, 0);
            acc[1][2] = __builtin_amdgcn_mfma_f32_32x32x16_bf16(a1, b2, acc[1][2], 0, 0, 0);
            acc[1][3] = __builtin_amdgcn_mfma_f32_32x32x16_bf16(a1, b3, acc[1][3], 0, 0, 0);
        }
    }

    // ---- epilogue: C/D col=lane31(w), row=(r&3)+8*(r>>2)+4*tau (+32*ci)
    const float* db = dynb + n * DIMS_;
#pragma unroll
    for (int ci = 0; ci < 2; ++ci) {
#pragma unroll
        for (int r = 0; r < 16; ++r) {
            const int co = 32 * ci + (r & 3) + 8 * (r >> 2) + 4 * tau;
            const float bco = db[co];
            float ps = 0.f, ps2 = 0.f;
#pragma unroll
            for (int s = 0; s < 4; ++s) {
                float z = acc[ci][s][r] + bco;
                size_t yi = ((size_t)(n * 64 + co) << 16) + ((size_t)t << 12)
                          + ((size_t)(hbase + 2 * wid + (s >> 1)) << 6) + (s & 1) * 32 + lane31;
                y[yi] = z;
                ps += z;
                ps2 += z * z;
            }
#pragma unroll
            for (int m = 1; m < 32; m <<= 1) {
                ps += __shfl_xor(ps, m, 64);
                ps2 += __shfl_xor(ps2, m, 64);
            }
            if (lane31 == 0) {
                atomicAdd(&bnred[co], ps);
                atomicAdd(&bnred[64 + co], ps2);
            }
        }
    }
    __syncthreads();
    if (tid < 128) atomicAdd(&sums[tid], bnred[tid]);
}

// ---------------------------------------------------------------------------
// 9) BN normalize + relu, float4, grid-stride, in place
__global__ void bn_norm4(const float* __restrict__ sums, const float* __restrict__ gamma,
                         const float* __restrict__ beta, float* __restrict__ y) {
    const float cnt = (float)(N_ * THW_);
    for (size_t idx = (size_t)blockIdx.x * 256 + threadIdx.x; idx < 8388608;
         idx += (size_t)4096 * 256) {
        int c = (int)((idx >> 14) & 63);
        float mean = sums[c] / cnt;
        float var = sums[64 + c] / cnt - mean * mean;
        float sc = gamma[c] * rsqrtf(var + 1e-5f);
        float sh = beta[c] - mean * sc;
        float4 v = ((float4*)y)[idx];
        v.x = fmaxf(fmaf(v.x, sc, sh), 0.f);
        v.y = fmaxf(fmaf(v.y, sc, sh), 0.f);
        v.z = fmaxf(fmaf(v.z, sc, sh), 0.f);
        v.w = fmaxf(fmaf(v.w, sc, sh), 0.f);
        ((float4*)y)[idx] = v;
    }
}

// ---------------------------------------------------------------------------
extern "C" void kernel_launch(void* const* d_in, const int* in_sizes, int n_in,
                              void* d_out, int out_size, void* d_ws, size_t ws_size,
                              hipStream_t stream) {
    const float* x       = (const float*)d_in[0];
    const float* weights = (const float*)d_in[1];
    const float* biases  = (const float*)d_in[2];
    const float* se_w1   = (const float*)d_in[3];
    const float* se_b1   = (const float*)d_in[4];
    const float* se_w2   = (const float*)d_in[5];
    const float* se_b2   = (const float*)d_in[6];
    const float* lin_w   = (const float*)d_in[7];
    const float* lin_b   = (const float*)d_in[8];
    const float* gamma   = (const float*)d_in[9];
    const float* beta    = (const float*)d_in[10];
    const int*   epochs  = (const int*)d_in[11];

    float* out = (float*)d_out;
    float* ws = (float*)d_ws;

    // workspace layout (float slots)
    const size_t STD_OFF  = 0;                        // 2,097,152
    const size_t H1_OFF   = STD_OFF + 2097152;        // 460,800
    const size_t SUMS_OFF = H1_OFF + 460800;          // 128
    const size_t POOL_OFF = SUMS_OFF + 128;           // 256
    const size_t PHI_OFF  = POOL_OFF + 256;           // 64 (unused)
    const size_t DYNB_OFF = PHI_OFF + 64;             // 512
    const size_t WTB_OFF  = DYNB_OFF + 512;           // 458,752 (bf16 x 917,504)
    const size_t W1T_OFF  = WTB_OFF + 458752;         // 25,600
    const size_t W2T_OFF  = W1T_OFF + 25600;          // 12,800
    const size_t XB_OFF   = W2T_OFF + 12800;          // 16,777,216 (bf16 x 33.5M)

    float* std_x  = ws + STD_OFF;
    float* h1     = ws + H1_OFF;
    float* sums   = ws + SUMS_OFF;
    float* pooled = ws + POOL_OFF;
    float* dynb   = ws + DYNB_OFF;
    unsigned short* wtb2 = (unsigned short*)(ws + WTB_OFF);
    float* w1t    = ws + W1T_OFF;
    float* w2t    = ws + W2T_OFF;
    unsigned short* xb = (unsigned short*)(ws + XB_OFF);

    stdxb_kernel<<<dim3(64, 8, 8), 512, 0, stream>>>(x, std_x, xb, sums, (unsigned*)pooled);
    wtrans<<<150, 256, 0, stream>>>(se_w1, se_w2, w1t, w2t);

    se_conv1c<<<dim3(57, 8, 2), 256, 0, stream>>>(std_x, w1t, se_b1, h1);
    se_conv2c<<<dim3(49, 8, 4), 256, 0, stream>>>(h1, w2t, se_b2, (unsigned*)pooled);

    dyn_w_head<<<432, 256, 0, stream>>>(weights, pooled, lin_w, lin_b, biases, epochs,
                                        wtb2, dynb);

    conv3d_mfma5<<<dim3(8, 16, 8), 256, 0, stream>>>(xb, wtb2, dynb, out, sums);

    bn_norm4<<<4096, 256, 0, stream>>>(sums, gamma, beta, out);
}